// Round 1
// baseline (291.938 us; speedup 1.0000x reference)
//
#include <hip/hip_runtime.h>
#include <stdint.h>

typedef unsigned short ushort_t;
typedef __attribute__((ext_vector_type(8))) short short8;
typedef __attribute__((ext_vector_type(4))) short short4v;
typedef __attribute__((ext_vector_type(4))) float f32x4;

#define DEV static __device__ __forceinline__

DEV unsigned short f2bf(float f) {
  unsigned u = __builtin_bit_cast(unsigned, f);
  u += 0x7fffu + ((u >> 16) & 1u);
  return (unsigned short)(u >> 16);
}
DEV float bf2f(unsigned short b) {
  return __builtin_bit_cast(float, (unsigned)b << 16);
}

DEV void gl16(const void* g, void* l) {
  __builtin_amdgcn_global_load_lds(
      (__attribute__((address_space(1))) char*)(unsigned long long)g,
      (__attribute__((address_space(3))) char*)(unsigned)(unsigned long long)l,
      16, 0, 0);
}

DEV f32x4 mfma_bf16(short8 a, short8 b, f32x4 c) {
  return __builtin_amdgcn_mfma_f32_16x16x32_bf16(a, b, c, 0, 0, 0);
}

// ---------------- converts ----------------
__global__ __launch_bounds__(256) void k_cvt(const float* __restrict__ in, ushort_t* __restrict__ out) {
  const int i = (blockIdx.x * 256 + threadIdx.x) * 4;
  const float4 v = *(const float4*)(in + i);
  short4v o;
  o.x = (short)f2bf(v.x); o.y = (short)f2bf(v.y); o.z = (short)f2bf(v.z); o.w = (short)f2bf(v.w);
  *(short4v*)(out + i) = o;
}

// Wg[:, :1024] strided -> contiguous bf16 [1024][1024]
__global__ __launch_bounds__(256) void k_cvt_wg1(const float* __restrict__ Wg, ushort_t* __restrict__ out) {
  const int i = blockIdx.x * 256 + threadIdx.x;  // 262144 threads
  const int r = i >> 8, c = (i & 255) * 4;
  const float4 v = *(const float4*)(Wg + (size_t)r * 2048 + c);
  short4v o;
  o.x = (short)f2bf(v.x); o.y = (short)f2bf(v.y); o.z = (short)f2bf(v.z); o.w = (short)f2bf(v.w);
  *(short4v*)(out + (size_t)r * 1024 + c) = o;
}

__global__ __launch_bounds__(256) void k_kgmean(const float* __restrict__ kg, float* __restrict__ out) {
  const int i = blockIdx.x * 256 + threadIdx.x;  // 2048
  const int b = i >> 10, d = i & 1023;
  float s = 0.f;
  #pragma unroll 4
  for (int e = 0; e < 256; e++) s += kg[((size_t)b * 256 + e) * 1024 + d];
  out[i] = s * (1.0f / 256.0f);
}

// g2[b][n] = bg[n] + sum_k kgmean[b][k] * Wg[n][1024+k]
__global__ __launch_bounds__(256) void k_g2(const float* __restrict__ kgm, const float* __restrict__ Wg,
                                            const float* __restrict__ bg, float* __restrict__ g2) {
  const int w = threadIdx.x >> 6, l = threadIdx.x & 63;
  const int idx = blockIdx.x * 4 + w;  // 2048
  const int b = idx >> 10, n = idx & 1023;
  const float* wr = Wg + (size_t)n * 2048 + 1024;
  const float* mb = kgm + b * 1024;
  float s = 0.f;
  #pragma unroll
  for (int j = 0; j < 16; j++) s += mb[j * 64 + l] * wr[j * 64 + l];
  #pragma unroll
  for (int m = 32; m >= 1; m >>= 1) s += __shfl_xor(s, m);
  if (l == 0) g2[idx] = s + bg[n];
}

// ---------------- GEMM: C[M,N] = A[M,1024] * Bw[N,1024]^T, bf16 MFMA ----------------
// MODE 0: A=x, Bw=[Wq;Wk;Wv]   -> Qg (scaled), Kaug(l-part), Vt(l-part)
// MODE 1: A=kg, Bw=[Wkk;Wkv]   -> Kaug(e-part), Vt(e-part)
// MODE 2: A=Og, Bw=[Wo;Wg1]    -> OUT bf16, GL bf16 (g2 added)
template <int MODE>
__global__ __launch_bounds__(256) void k_gemm(
    const ushort_t* __restrict__ A, const ushort_t* __restrict__ Bw,
    const float* __restrict__ bias0, const float* __restrict__ bias1, const float* __restrict__ bias2,
    const float* __restrict__ g2v,
    ushort_t* __restrict__ o0, ushort_t* __restrict__ o1, ushort_t* __restrict__ o2) {
  __shared__ __align__(16) ushort_t As[2][128 * 32];
  __shared__ __align__(16) ushort_t Bs[2][128 * 32];
  const int tid = threadIdx.x;
  const int w = tid >> 6, l = tid & 63;
  const int wr = w >> 1, wc = w & 1;
  const int fr = l & 15, fg = l >> 4;
  const int m0 = blockIdx.x * 128, n0 = blockIdx.y * 128;
  const int srow = tid >> 2, sseg = tid & 3;
  const ushort_t* ga = A + (size_t)(m0 + srow) * 1024 + sseg * 8;
  const ushort_t* gb = Bw + (size_t)(n0 + srow) * 1024 + sseg * 8;
  f32x4 acc[4][4] = {};

  auto stage = [&](int nb, int kt) {
    char* lA = (char*)&As[nb][0] + w * 1024;
    char* lB = (char*)&Bs[nb][0] + w * 1024;
    const ushort_t* gA = ga + kt * 32;
    const ushort_t* gB = gb + kt * 32;
    gl16(gA, lA);
    gl16(gA + 64 * 1024, lA + 4096);
    gl16(gB, lB);
    gl16(gB + 64 * 1024, lB + 4096);
  };

  stage(0, 0);
  __syncthreads();
  int cur = 0;
  for (int kt = 0; kt < 32; kt++) {
    if (kt < 31) stage(cur ^ 1, kt + 1);
    const short* Ab = (const short*)&As[cur][0];
    const short* Bb = (const short*)&Bs[cur][0];
    short8 af[4], bfr[4];
    #pragma unroll
    for (int i = 0; i < 4; i++) {
      af[i]  = *(const short8*)(Ab + (wr * 64 + i * 16 + fr) * 32 + fg * 8);
      bfr[i] = *(const short8*)(Bb + (wc * 64 + i * 16 + fr) * 32 + fg * 8);
    }
    #pragma unroll
    for (int i = 0; i < 4; i++)
      #pragma unroll
      for (int j = 0; j < 4; j++)
        acc[i][j] = mfma_bf16(af[i], bfr[j], acc[i][j]);
    __syncthreads();
    cur ^= 1;
  }

  const int sec = n0 >> 10;
  #pragma unroll
  for (int i = 0; i < 4; i++) {
    #pragma unroll
    for (int j = 0; j < 4; j++) {
      #pragma unroll
      for (int r = 0; r < 4; r++) {
        const int m = m0 + wr * 64 + i * 16 + fg * 4 + r;
        const int nn = (n0 & 1023) + wc * 64 + j * 16 + fr;
        const int h = nn >> 6, d = nn & 63;
        const float v = acc[i][j][r];
        if constexpr (MODE == 0) {
          const int b = m >> 11, lq = m & 2047;
          if (sec == 0)
            o0[((size_t)(b * 16 + h) * 2048 + lq) * 64 + d] = f2bf((v + bias0[nn]) * 0.125f);
          else if (sec == 1)
            o1[((size_t)(b * 16 + h) * 2304 + lq) * 64 + d] = f2bf(v + bias1[nn]);
          else
            o2[((size_t)(b * 16 + h) * 64 + d) * 2304 + lq] = f2bf(v + bias2[nn]);
        } else if constexpr (MODE == 1) {
          const int b = m >> 8, e = m & 255;
          if (sec == 0)
            o1[((size_t)(b * 16 + h) * 2304 + 2048 + e) * 64 + d] = f2bf(v + bias0[nn]);
          else
            o2[((size_t)(b * 16 + h) * 64 + d) * 2304 + 2048 + e] = f2bf(v + bias1[nn]);
        } else {
          const int b = m >> 11;
          if (sec == 0)
            o0[(size_t)m * 1024 + nn] = f2bf(v + bias0[nn]);
          else
            o1[(size_t)m * 1024 + nn] = f2bf(v + g2v[b * 1024 + nn]);
        }
      }
    }
  }
}

// ---------------- flash attention ----------------
// Qg [bh][2048][64], Kg [bh][2304][64], Vtg [bh][64][2304], Og [b*2048][1024] (all bf16)
__global__ __launch_bounds__(256) void k_attn(
    const ushort_t* __restrict__ Qg, const ushort_t* __restrict__ Kg,
    const ushort_t* __restrict__ Vtg, ushort_t* __restrict__ Og) {
  __shared__ __align__(16) ushort_t Ks[64 * 64];      // XOR-swizzled [kv][d]
  __shared__ __align__(16) ushort_t Vs[64 * 72];      // [d][kv], padded
  __shared__ __align__(16) ushort_t Ps[4][16 * 72];   // per-wave P, padded
  const int tid = threadIdx.x;
  const int w = tid >> 6, l = tid & 63;
  const int fr = l & 15, fg = l >> 4;
  const int bh = blockIdx.y;
  const int q0 = blockIdx.x * 64;

  const ushort_t* qrow = Qg + ((size_t)bh * 2048 + q0 + w * 16 + fr) * 64;
  const short8 qf0 = *(const short8*)((const short*)qrow + fg * 8);
  const short8 qf1 = *(const short8*)((const short*)qrow + 32 + fg * 8);

  f32x4 o[4] = {};
  float mrun[4], lrun[4];
  #pragma unroll
  for (int r = 0; r < 4; r++) { mrun[r] = -3.0e30f; lrun[r] = 0.f; }

  const int srow = tid >> 2, sseg = tid & 3;
  const ushort_t* kgb = Kg + ((size_t)bh * 2304 + srow) * 64 + sseg * 16;
  const ushort_t* vgb = Vtg + ((size_t)bh * 64 + srow) * 2304 + sseg * 16;
  const int kswz = (srow & 7) << 4;

  for (int mt = 0; mt < 36; mt++) {
    const int m0 = mt * 64;
    {
      const short8 ka = *(const short8*)(kgb + (size_t)m0 * 64);
      const short8 kb = *(const short8*)(kgb + (size_t)m0 * 64 + 8);
      const short8 va = *(const short8*)(vgb + m0);
      const short8 vb = *(const short8*)(vgb + m0 + 8);
      const int kb0 = srow * 128 + sseg * 32;
      *(short8*)((char*)Ks + (kb0 ^ kswz)) = ka;
      *(short8*)((char*)Ks + ((kb0 + 16) ^ kswz)) = kb;
      char* vdst = (char*)Vs + srow * 144 + sseg * 32;
      *(short8*)(vdst) = va;
      *(short8*)(vdst + 16) = vb;
    }
    __syncthreads();

    f32x4 s[4];
    #pragma unroll
    for (int t = 0; t < 4; t++) {
      const int row = t * 16 + fr;
      const int ba = row * 128 + fg * 16;
      const int sw = (row & 7) << 4;
      const short8 k0 = *(const short8*)((const char*)Ks + (ba ^ sw));
      const short8 k1 = *(const short8*)((const char*)Ks + ((ba + 64) ^ sw));
      f32x4 z = {};
      z = mfma_bf16(qf0, k0, z);
      z = mfma_bf16(qf1, k1, z);
      s[t] = z;
    }

    float alpha[4];
    #pragma unroll
    for (int r = 0; r < 4; r++) {
      float mx = fmaxf(fmaxf(s[0][r], s[1][r]), fmaxf(s[2][r], s[3][r]));
      mx = fmaxf(mx, __shfl_xor(mx, 1));
      mx = fmaxf(mx, __shfl_xor(mx, 2));
      mx = fmaxf(mx, __shfl_xor(mx, 4));
      mx = fmaxf(mx, __shfl_xor(mx, 8));
      const float mn = fmaxf(mrun[r], mx);
      alpha[r] = __expf(mrun[r] - mn);
      mrun[r] = mn;
      float sm = 0.f;
      #pragma unroll
      for (int t = 0; t < 4; t++) {
        const float p = __expf(s[t][r] - mn);
        s[t][r] = p;
        sm += p;
      }
      sm += __shfl_xor(sm, 1);
      sm += __shfl_xor(sm, 2);
      sm += __shfl_xor(sm, 4);
      sm += __shfl_xor(sm, 8);
      lrun[r] = lrun[r] * alpha[r] + sm;
      #pragma unroll
      for (int t = 0; t < 4; t++) o[t][r] *= alpha[r];
    }

    ushort_t* pw = &Ps[w][0];
    #pragma unroll
    for (int t = 0; t < 4; t++)
      #pragma unroll
      for (int r = 0; r < 4; r++)
        pw[(fg * 4 + r) * 72 + t * 16 + fr] = f2bf(s[t][r]);

    #pragma unroll
    for (int c = 0; c < 2; c++) {
      const short8 pf = *(const short8*)((const short*)pw + fr * 72 + c * 32 + fg * 8);
      #pragma unroll
      for (int t2 = 0; t2 < 4; t2++) {
        const short8 vf = *(const short8*)((const short*)Vs + (t2 * 16 + fr) * 72 + c * 32 + fg * 8);
        o[t2] = mfma_bf16(pf, vf, o[t2]);
      }
    }
    __syncthreads();
  }

  const int b = bh >> 4, h = bh & 15;
  #pragma unroll
  for (int r = 0; r < 4; r++) {
    const float inv = 1.0f / lrun[r];
    const int q = q0 + w * 16 + fg * 4 + r;
    ushort_t* orow = Og + ((size_t)b * 2048 + q) * 1024 + h * 64;
    #pragma unroll
    for (int t = 0; t < 4; t++) orow[t * 16 + fr] = f2bf(o[t][r] * inv);
  }
}

// ---------------- final mix ----------------
__global__ __launch_bounds__(256) void k_final(const float* __restrict__ x,
                                               const ushort_t* __restrict__ OUT,
                                               const ushort_t* __restrict__ GL,
                                               float* __restrict__ y) {
  const int i = (blockIdx.x * 256 + threadIdx.x) * 4;
  const float4 xv = *(const float4*)(x + i);
  const short4v ov = *(const short4v*)((const short*)OUT + i);
  const short4v gv = *(const short4v*)((const short*)GL + i);
  float4 r;
  {
    const float o0 = bf2f((unsigned short)ov.x);
    const float g0 = 1.f / (1.f + __expf(-bf2f((unsigned short)gv.x)));
    r.x = xv.x + g0 * (o0 - xv.x);
  }
  {
    const float o1 = bf2f((unsigned short)ov.y);
    const float g1 = 1.f / (1.f + __expf(-bf2f((unsigned short)gv.y)));
    r.y = xv.y + g1 * (o1 - xv.y);
  }
  {
    const float o2 = bf2f((unsigned short)ov.z);
    const float g2 = 1.f / (1.f + __expf(-bf2f((unsigned short)gv.z)));
    r.z = xv.z + g2 * (o2 - xv.z);
  }
  {
    const float o3 = bf2f((unsigned short)ov.w);
    const float g3 = 1.f / (1.f + __expf(-bf2f((unsigned short)gv.w)));
    r.w = xv.w + g3 * (o3 - xv.w);
  }
  *(float4*)(y + i) = r;
}

extern "C" void kernel_launch(void* const* d_in, const int* in_sizes, int n_in,
                              void* d_out, int out_size, void* d_ws, size_t ws_size,
                              hipStream_t stream) {
  (void)in_sizes; (void)n_in; (void)out_size; (void)ws_size;
  const float* x   = (const float*)d_in[0];
  const float* kg  = (const float*)d_in[1];
  const float* Wq  = (const float*)d_in[2];
  const float* bq  = (const float*)d_in[3];
  const float* Wk  = (const float*)d_in[4];
  const float* bk  = (const float*)d_in[5];
  const float* Wv  = (const float*)d_in[6];
  const float* bv  = (const float*)d_in[7];
  const float* Wkk = (const float*)d_in[8];
  const float* bkk = (const float*)d_in[9];
  const float* Wkv = (const float*)d_in[10];
  const float* bkv = (const float*)d_in[11];
  const float* Wo  = (const float*)d_in[12];
  const float* bo  = (const float*)d_in[13];
  const float* Wg  = (const float*)d_in[14];
  const float* bg  = (const float*)d_in[15];
  float* y = (float*)d_out;

  char* ws = (char*)d_ws;
  size_t off = 0;
  auto take = [&](size_t bytes) {
    char* p = ws + off;
    off += (bytes + 255) & ~(size_t)255;
    return p;
  };
  ushort_t* xh   = (ushort_t*)take((size_t)4096 * 1024 * 2);
  ushort_t* kgh  = (ushort_t*)take((size_t)512 * 1024 * 2);
  ushort_t* WB1  = (ushort_t*)take((size_t)3072 * 1024 * 2);
  ushort_t* WB2  = (ushort_t*)take((size_t)2048 * 1024 * 2);
  ushort_t* WB3  = (ushort_t*)take((size_t)2048 * 1024 * 2);
  ushort_t* Qg   = (ushort_t*)take((size_t)32 * 2048 * 64 * 2);
  ushort_t* Kaug = (ushort_t*)take((size_t)32 * 2304 * 64 * 2);
  ushort_t* Vt   = (ushort_t*)take((size_t)32 * 2304 * 64 * 2);
  ushort_t* Og   = (ushort_t*)take((size_t)4096 * 1024 * 2);
  ushort_t* OUTb = (ushort_t*)take((size_t)4096 * 1024 * 2);
  ushort_t* GLb  = (ushort_t*)take((size_t)4096 * 1024 * 2);
  float* kgm     = (float*)take(2048 * 4);
  float* g2      = (float*)take(2048 * 4);

  k_cvt<<<4096, 256, 0, stream>>>(x, xh);
  k_cvt<<<512, 256, 0, stream>>>(kg, kgh);
  k_cvt<<<1024, 256, 0, stream>>>(Wq, WB1);
  k_cvt<<<1024, 256, 0, stream>>>(Wk, WB1 + 1048576);
  k_cvt<<<1024, 256, 0, stream>>>(Wv, WB1 + 2097152);
  k_cvt<<<1024, 256, 0, stream>>>(Wkk, WB2);
  k_cvt<<<1024, 256, 0, stream>>>(Wkv, WB2 + 1048576);
  k_cvt<<<1024, 256, 0, stream>>>(Wo, WB3);
  k_cvt_wg1<<<1024, 256, 0, stream>>>(Wg, WB3 + 1048576);
  k_kgmean<<<8, 256, 0, stream>>>(kg, kgm);
  k_g2<<<512, 256, 0, stream>>>(kgm, Wg, bg, g2);

  k_gemm<0><<<dim3(32, 24), 256, 0, stream>>>(xh, WB1, bq, bk, bv, nullptr, Qg, Kaug, Vt);
  k_gemm<1><<<dim3(4, 16), 256, 0, stream>>>(kgh, WB2, bkk, bkv, nullptr, nullptr, nullptr, Kaug, Vt);
  k_attn<<<dim3(32, 32), 256, 0, stream>>>(Qg, Kaug, Vt, Og);
  k_gemm<2><<<dim3(32, 16), 256, 0, stream>>>(Og, WB3, bo, nullptr, nullptr, g2, OUTb, GLb, nullptr);
  k_final<<<4096, 256, 0, stream>>>(x, OUTb, GLb, y);
}

// Round 2
// 262.661 us; speedup vs baseline: 1.1115x; 1.1115x over previous
//
#include <hip/hip_runtime.h>
#include <stdint.h>

typedef unsigned short ushort_t;
typedef __attribute__((ext_vector_type(8))) short short8;
typedef __attribute__((ext_vector_type(4))) short short4v;
typedef __attribute__((ext_vector_type(4))) float f32x4;

#define DEV static __device__ __forceinline__

DEV unsigned short f2bf(float f) {
  unsigned u = __builtin_bit_cast(unsigned, f);
  u += 0x7fffu + ((u >> 16) & 1u);
  return (unsigned short)(u >> 16);
}
DEV float bf2f(unsigned short b) {
  return __builtin_bit_cast(float, (unsigned)b << 16);
}

DEV void gl16(const void* g, void* l) {
  __builtin_amdgcn_global_load_lds(
      (__attribute__((address_space(1))) char*)(unsigned long long)g,
      (__attribute__((address_space(3))) char*)(unsigned)(unsigned long long)l,
      16, 0, 0);
}

DEV f32x4 mfma_bf16(short8 a, short8 b, f32x4 c) {
  return __builtin_amdgcn_mfma_f32_16x16x32_bf16(a, b, c, 0, 0, 0);
}

// ---------------- consolidated converts ----------------
// segments (1024 f32 elems per block):
// x[0,4096) kg[4096,4608) Wq[4608,5632) Wk[5632,6656) Wv[6656,7680)
// Wkk[7680,8704) Wkv[8704,9728) Wo[9728,10752) Wg1(strided)[10752,11776)
__global__ __launch_bounds__(256) void k_cvt_all(
    const float* __restrict__ x, const float* __restrict__ kg,
    const float* __restrict__ Wq, const float* __restrict__ Wk, const float* __restrict__ Wv,
    const float* __restrict__ Wkk, const float* __restrict__ Wkv,
    const float* __restrict__ Wo, const float* __restrict__ Wg,
    ushort_t* __restrict__ xh, ushort_t* __restrict__ kgh,
    ushort_t* __restrict__ WB1, ushort_t* __restrict__ WB2, ushort_t* __restrict__ WB3) {
  const int b = blockIdx.x;
  if (b >= 10752) {
    // Wg[:, :1024] strided -> WB3 + 1M, bf16 [1024][1024]
    const int i = (b - 10752) * 256 + threadIdx.x;
    const int r = i >> 8, c = (i & 255) * 4;
    const float4 v = *(const float4*)(Wg + (size_t)r * 2048 + c);
    short4v o;
    o.x = (short)f2bf(v.x); o.y = (short)f2bf(v.y); o.z = (short)f2bf(v.z); o.w = (short)f2bf(v.w);
    *(short4v*)(WB3 + 1048576 + (size_t)r * 1024 + c) = o;
    return;
  }
  const float* src;
  ushort_t* dst;
  int off;
  if (b < 4096)       { src = x;   dst = xh;            off = b; }
  else if (b < 4608)  { src = kg;  dst = kgh;           off = b - 4096; }
  else if (b < 5632)  { src = Wq;  dst = WB1;           off = b - 4608; }
  else if (b < 6656)  { src = Wk;  dst = WB1 + 1048576; off = b - 5632; }
  else if (b < 7680)  { src = Wv;  dst = WB1 + 2097152; off = b - 6656; }
  else if (b < 8704)  { src = Wkk; dst = WB2;           off = b - 7680; }
  else if (b < 9728)  { src = Wkv; dst = WB2 + 1048576; off = b - 8704; }
  else                { src = Wo;  dst = WB3;           off = b - 9728; }
  const int i = off * 1024 + threadIdx.x * 4;
  const float4 v = *(const float4*)(src + i);
  short4v o;
  o.x = (short)f2bf(v.x); o.y = (short)f2bf(v.y); o.z = (short)f2bf(v.z); o.w = (short)f2bf(v.w);
  *(short4v*)(dst + i) = o;
}

__global__ __launch_bounds__(256) void k_kgmean(const float* __restrict__ kg, float* __restrict__ out) {
  const int i = blockIdx.x * 256 + threadIdx.x;  // 2048
  const int b = i >> 10, d = i & 1023;
  float s = 0.f;
  #pragma unroll 4
  for (int e = 0; e < 256; e++) s += kg[((size_t)b * 256 + e) * 1024 + d];
  out[i] = s * (1.0f / 256.0f);
}

// g2[b][n] = bg[n] + sum_k kgmean[b][k] * Wg[n][1024+k]
__global__ __launch_bounds__(256) void k_g2(const float* __restrict__ kgm, const float* __restrict__ Wg,
                                            const float* __restrict__ bg, float* __restrict__ g2) {
  const int w = threadIdx.x >> 6, l = threadIdx.x & 63;
  const int idx = blockIdx.x * 4 + w;  // 2048
  const int b = idx >> 10, n = idx & 1023;
  const float* wr = Wg + (size_t)n * 2048 + 1024;
  const float* mb = kgm + b * 1024;
  float s = 0.f;
  #pragma unroll
  for (int j = 0; j < 16; j++) s += mb[j * 64 + l] * wr[j * 64 + l];
  #pragma unroll
  for (int m = 32; m >= 1; m >>= 1) s += __shfl_xor(s, m);
  if (l == 0) g2[idx] = s + bg[n];
}

// ---------------- GEMM: C[M,N] = A[M,1024] * Bw[N,1024]^T, bf16 MFMA ----------------
template <int MODE>
__global__ __launch_bounds__(256) void k_gemm(
    const ushort_t* __restrict__ A, const ushort_t* __restrict__ Bw,
    const float* __restrict__ bias0, const float* __restrict__ bias1, const float* __restrict__ bias2,
    const float* __restrict__ g2v,
    ushort_t* __restrict__ o0, ushort_t* __restrict__ o1, ushort_t* __restrict__ o2) {
  __shared__ __align__(16) ushort_t As[2][128 * 32];
  __shared__ __align__(16) ushort_t Bs[2][128 * 32];
  const int tid = threadIdx.x;
  const int w = tid >> 6, l = tid & 63;
  const int wr = w >> 1, wc = w & 1;
  const int fr = l & 15, fg = l >> 4;
  const int m0 = blockIdx.x * 128, n0 = blockIdx.y * 128;
  const int srow = tid >> 2, sseg = tid & 3;
  const ushort_t* ga = A + (size_t)(m0 + srow) * 1024 + sseg * 8;
  const ushort_t* gb = Bw + (size_t)(n0 + srow) * 1024 + sseg * 8;
  f32x4 acc[4][4] = {};

  auto stage = [&](int nb, int kt) {
    char* lA = (char*)&As[nb][0] + w * 1024;
    char* lB = (char*)&Bs[nb][0] + w * 1024;
    const ushort_t* gA = ga + kt * 32;
    const ushort_t* gB = gb + kt * 32;
    gl16(gA, lA);
    gl16(gA + 64 * 1024, lA + 4096);
    gl16(gB, lB);
    gl16(gB + 64 * 1024, lB + 4096);
  };

  stage(0, 0);
  __syncthreads();
  int cur = 0;
  for (int kt = 0; kt < 32; kt++) {
    if (kt < 31) stage(cur ^ 1, kt + 1);
    const short* Ab = (const short*)&As[cur][0];
    const short* Bb = (const short*)&Bs[cur][0];
    short8 af[4], bfr[4];
    #pragma unroll
    for (int i = 0; i < 4; i++) {
      af[i]  = *(const short8*)(Ab + (wr * 64 + i * 16 + fr) * 32 + fg * 8);
      bfr[i] = *(const short8*)(Bb + (wc * 64 + i * 16 + fr) * 32 + fg * 8);
    }
    #pragma unroll
    for (int i = 0; i < 4; i++)
      #pragma unroll
      for (int j = 0; j < 4; j++)
        acc[i][j] = mfma_bf16(af[i], bfr[j], acc[i][j]);
    __syncthreads();
    cur ^= 1;
  }

  const int sec = n0 >> 10;
  #pragma unroll
  for (int i = 0; i < 4; i++) {
    #pragma unroll
    for (int j = 0; j < 4; j++) {
      #pragma unroll
      for (int r = 0; r < 4; r++) {
        const int m = m0 + wr * 64 + i * 16 + fg * 4 + r;
        const int nn = (n0 & 1023) + wc * 64 + j * 16 + fr;
        const int h = nn >> 6, d = nn & 63;
        const float v = acc[i][j][r];
        if constexpr (MODE == 0) {
          const int b = m >> 11, lq = m & 2047;
          if (sec == 0)
            o0[((size_t)(b * 16 + h) * 2048 + lq) * 64 + d] = f2bf((v + bias0[nn]) * 0.18033688f); // 0.125*log2e
          else if (sec == 1)
            o1[((size_t)(b * 16 + h) * 2304 + lq) * 64 + d] = f2bf(v + bias1[nn]);
          else
            o2[((size_t)(b * 16 + h) * 64 + d) * 2304 + lq] = f2bf(v + bias2[nn]);
        } else if constexpr (MODE == 1) {
          const int b = m >> 8, e = m & 255;
          if (sec == 0)
            o1[((size_t)(b * 16 + h) * 2304 + 2048 + e) * 64 + d] = f2bf(v + bias0[nn]);
          else
            o2[((size_t)(b * 16 + h) * 64 + d) * 2304 + 2048 + e] = f2bf(v + bias1[nn]);
        } else {
          const int b = m >> 11;
          if (sec == 0)
            o0[(size_t)m * 1024 + nn] = f2bf(v + bias0[nn]);
          else
            o1[(size_t)m * 1024 + nn] = f2bf(v + g2v[b * 1024 + nn]);
        }
      }
    }
  }
}

// ---------------- flash attention (pipelined, QBLK=128) ----------------
// Qg [bh][2048][64] (pre-scaled by 0.125*log2e), Kg [bh][2304][64], Vtg [bh][64][2304],
// Og [b*2048][1024] (all bf16). exp in base-2 domain.
__global__ __launch_bounds__(256, 2) void k_attn(
    const ushort_t* __restrict__ Qg, const ushort_t* __restrict__ Kg,
    const ushort_t* __restrict__ Vtg, ushort_t* __restrict__ Og) {
  __shared__ __align__(16) ushort_t Ks[2][64 * 64];   // XOR-swizzled [kv][d]
  __shared__ __align__(16) ushort_t Vs[2][64 * 64];   // XOR-swizzled [d][kv]
  __shared__ __align__(16) ushort_t Ps[4][32 * 64];   // per-wave P, XOR-swizzled [q][kv]
  const int tid = threadIdx.x;
  const int w = tid >> 6, l = tid & 63;
  const int fr = l & 15, fg = l >> 4;
  const int bh = blockIdx.y;
  const int q0 = blockIdx.x * 128 + w * 32;

  // Q fragments: qf[i][c] = Q[q0 + i*16 + fr][c*32 + fg*8 ..+8]
  short8 qf[2][2];
  #pragma unroll
  for (int i = 0; i < 2; i++) {
    const short* qrow = (const short*)(Qg + ((size_t)bh * 2048 + q0 + i * 16 + fr) * 64);
    qf[i][0] = *(const short8*)(qrow + fg * 8);
    qf[i][1] = *(const short8*)(qrow + 32 + fg * 8);
  }

  f32x4 o[2][4] = {};
  float mrun[2][4], lpart[2][4];
  #pragma unroll
  for (int i = 0; i < 2; i++)
    #pragma unroll
    for (int r = 0; r < 4; r++) { mrun[i][r] = -1.0e30f; lpart[i][r] = 0.f; }

  const int srow = tid >> 2, sseg = tid & 3;
  const ushort_t* kgb = Kg + ((size_t)bh * 2304 + srow) * 64 + sseg * 16;
  const ushort_t* vgb = Vtg + ((size_t)bh * 64 + srow) * 2304 + sseg * 16;
  const int sdst = srow * 128 + sseg * 32;
  const int sswz = (srow & 7) << 4;

  // prologue: stage tile 0
  {
    const short8 ka = *(const short8*)(kgb);
    const short8 kb = *(const short8*)(kgb + 8);
    const short8 va = *(const short8*)(vgb);
    const short8 vb = *(const short8*)(vgb + 8);
    *(short8*)((char*)&Ks[0][0] + (sdst ^ sswz)) = ka;
    *(short8*)((char*)&Ks[0][0] + ((sdst + 16) ^ sswz)) = kb;
    *(short8*)((char*)&Vs[0][0] + (sdst ^ sswz)) = va;
    *(short8*)((char*)&Vs[0][0] + ((sdst + 16) ^ sswz)) = vb;
  }

  const int pswz = (fr & 7) << 4;
  ushort_t* pw = &Ps[w][0];

  for (int mt = 0; mt < 36; mt++) {
    __syncthreads();  // buf[mt&1] ready; everyone done reading buf[(mt+1)&1]

    // issue prefetch of tile mt+1 into registers (latency hides under compute)
    short8 krn0, krn1, vrn0, vrn1;
    if (mt < 35) {
      const size_t ko = (size_t)(mt + 1) * 4096;
      krn0 = *(const short8*)(kgb + ko);
      krn1 = *(const short8*)(kgb + ko + 8);
      vrn0 = *(const short8*)(vgb + (mt + 1) * 64);
      vrn1 = *(const short8*)(vgb + (mt + 1) * 64 + 8);
    }

    const char* Kb = (const char*)&Ks[mt & 1][0];
    const char* Vb = (const char*)&Vs[mt & 1][0];

    // QK^T: s[i][t] covers q rows i*16.., kv cols t*16..
    f32x4 s[2][4];
    #pragma unroll
    for (int t = 0; t < 4; t++) {
      const int rb = (t * 16 + fr) * 128 + fg * 16;
      const short8 k0 = *(const short8*)(Kb + (rb ^ pswz));
      const short8 k1 = *(const short8*)(Kb + ((rb + 64) ^ pswz));
      #pragma unroll
      for (int i = 0; i < 2; i++) {
        f32x4 z = {};
        z = mfma_bf16(qf[i][0], k0, z);
        z = mfma_bf16(qf[i][1], k1, z);
        s[i][t] = z;
      }
    }

    // online softmax (base-2), defer-max, deferred l-reduction
    float mx[2][4];
    float need = 0.f;
    #pragma unroll
    for (int i = 0; i < 2; i++) {
      #pragma unroll
      for (int r = 0; r < 4; r++) {
        float m = fmaxf(fmaxf(s[i][0][r], s[i][1][r]), fmaxf(s[i][2][r], s[i][3][r]));
        m = fmaxf(m, __shfl_xor(m, 1));
        m = fmaxf(m, __shfl_xor(m, 2));
        m = fmaxf(m, __shfl_xor(m, 4));
        m = fmaxf(m, __shfl_xor(m, 8));
        mx[i][r] = m;
        need = fmaxf(need, m - mrun[i][r]);
      }
    }
    if (__any(need > 11.5416f)) {  // 8*log2e
      #pragma unroll
      for (int i = 0; i < 2; i++) {
        #pragma unroll
        for (int r = 0; r < 4; r++) {
          const float mn = fmaxf(mrun[i][r], mx[i][r]);
          const float al = exp2f(mrun[i][r] - mn);
          mrun[i][r] = mn;
          lpart[i][r] *= al;
          #pragma unroll
          for (int dt = 0; dt < 4; dt++) o[i][dt][r] *= al;
        }
      }
    }
    #pragma unroll
    for (int i = 0; i < 2; i++) {
      #pragma unroll
      for (int r = 0; r < 4; r++) {
        float sm = 0.f;
        #pragma unroll
        for (int t = 0; t < 4; t++) {
          const float p = exp2f(s[i][t][r] - mrun[i][r]);
          s[i][t][r] = p;
          sm += p;
        }
        lpart[i][r] += sm;  // cross-lane reduce deferred to epilogue
      }
    }

    // P -> LDS (C-layout -> A-frag layout), swizzled
    #pragma unroll
    for (int i = 0; i < 2; i++) {
      #pragma unroll
      for (int r = 0; r < 4; r++) {
        const int row = i * 16 + fg * 4 + r;
        const int rb = row * 128;
        const int rs = (row & 7) << 4;
        #pragma unroll
        for (int t = 0; t < 4; t++)
          *(ushort_t*)((char*)pw + ((rb + (t * 16 + fr) * 2) ^ rs)) = f2bf(s[i][t][r]);
      }
    }

    // PV: o[i][dt] += P[i-rows][kv] * V[dt-cols][kv]
    #pragma unroll
    for (int c = 0; c < 2; c++) {
      short8 pf[2];
      #pragma unroll
      for (int i = 0; i < 2; i++)
        pf[i] = *(const short8*)((const char*)pw + ((((i * 16 + fr) * 128) + fg * 16 + c * 64) ^ pswz));
      #pragma unroll
      for (int dt = 0; dt < 4; dt++) {
        const short8 vf = *(const short8*)(Vb + ((((dt * 16 + fr) * 128) + fg * 16 + c * 64) ^ pswz));
        o[0][dt] = mfma_bf16(pf[0], vf, o[0][dt]);
        o[1][dt] = mfma_bf16(pf[1], vf, o[1][dt]);
      }
    }

    // stage tile mt+1 into the other buffer (after compute; visible after next barrier)
    if (mt < 35) {
      char* Kd = (char*)&Ks[(mt + 1) & 1][0];
      char* Vd = (char*)&Vs[(mt + 1) & 1][0];
      *(short8*)(Kd + (sdst ^ sswz)) = krn0;
      *(short8*)(Kd + ((sdst + 16) ^ sswz)) = krn1;
      *(short8*)(Vd + (sdst ^ sswz)) = vrn0;
      *(short8*)(Vd + ((sdst + 16) ^ sswz)) = vrn1;
    }
  }

  const int b = bh >> 4, h = bh & 15;
  #pragma unroll
  for (int i = 0; i < 2; i++) {
    #pragma unroll
    for (int r = 0; r < 4; r++) {
      float ls = lpart[i][r];
      ls += __shfl_xor(ls, 1);
      ls += __shfl_xor(ls, 2);
      ls += __shfl_xor(ls, 4);
      ls += __shfl_xor(ls, 8);
      const float inv = 1.0f / ls;
      const int q = q0 + i * 16 + fg * 4 + r;
      ushort_t* orow = Og + ((size_t)b * 2048 + q) * 1024 + h * 64;
      #pragma unroll
      for (int dt = 0; dt < 4; dt++) orow[dt * 16 + fr] = f2bf(o[i][dt][r] * inv);
    }
  }
}

// ---------------- final mix ----------------
__global__ __launch_bounds__(256) void k_final(const float* __restrict__ x,
                                               const ushort_t* __restrict__ OUT,
                                               const ushort_t* __restrict__ GL,
                                               float* __restrict__ y) {
  const int i = (blockIdx.x * 256 + threadIdx.x) * 4;
  const float4 xv = *(const float4*)(x + i);
  const short4v ov = *(const short4v*)((const short*)OUT + i);
  const short4v gv = *(const short4v*)((const short*)GL + i);
  float4 r;
  {
    const float o0 = bf2f((unsigned short)ov.x);
    const float g0 = 1.f / (1.f + __expf(-bf2f((unsigned short)gv.x)));
    r.x = xv.x + g0 * (o0 - xv.x);
  }
  {
    const float o1 = bf2f((unsigned short)ov.y);
    const float g1 = 1.f / (1.f + __expf(-bf2f((unsigned short)gv.y)));
    r.y = xv.y + g1 * (o1 - xv.y);
  }
  {
    const float o2 = bf2f((unsigned short)ov.z);
    const float g2 = 1.f / (1.f + __expf(-bf2f((unsigned short)gv.z)));
    r.z = xv.z + g2 * (o2 - xv.z);
  }
  {
    const float o3 = bf2f((unsigned short)ov.w);
    const float g3 = 1.f / (1.f + __expf(-bf2f((unsigned short)gv.w)));
    r.w = xv.w + g3 * (o3 - xv.w);
  }
  *(float4*)(y + i) = r;
}

extern "C" void kernel_launch(void* const* d_in, const int* in_sizes, int n_in,
                              void* d_out, int out_size, void* d_ws, size_t ws_size,
                              hipStream_t stream) {
  (void)in_sizes; (void)n_in; (void)out_size; (void)ws_size;
  const float* x   = (const float*)d_in[0];
  const float* kg  = (const float*)d_in[1];
  const float* Wq  = (const float*)d_in[2];
  const float* bq  = (const float*)d_in[3];
  const float* Wk  = (const float*)d_in[4];
  const float* bk  = (const float*)d_in[5];
  const float* Wv  = (const float*)d_in[6];
  const float* bv  = (const float*)d_in[7];
  const float* Wkk = (const float*)d_in[8];
  const float* bkk = (const float*)d_in[9];
  const float* Wkv = (const float*)d_in[10];
  const float* bkv = (const float*)d_in[11];
  const float* Wo  = (const float*)d_in[12];
  const float* bo  = (const float*)d_in[13];
  const float* Wg  = (const float*)d_in[14];
  const float* bg  = (const float*)d_in[15];
  float* y = (float*)d_out;

  char* ws = (char*)d_ws;
  size_t off = 0;
  auto take = [&](size_t bytes) {
    char* p = ws + off;
    off += (bytes + 255) & ~(size_t)255;
    return p;
  };
  ushort_t* xh   = (ushort_t*)take((size_t)4096 * 1024 * 2);
  ushort_t* kgh  = (ushort_t*)take((size_t)512 * 1024 * 2);
  ushort_t* WB1  = (ushort_t*)take((size_t)3072 * 1024 * 2);
  ushort_t* WB2  = (ushort_t*)take((size_t)2048 * 1024 * 2);
  ushort_t* WB3  = (ushort_t*)take((size_t)2048 * 1024 * 2);
  ushort_t* Qg   = (ushort_t*)take((size_t)32 * 2048 * 64 * 2);
  ushort_t* Kaug = (ushort_t*)take((size_t)32 * 2304 * 64 * 2);
  ushort_t* Vt   = (ushort_t*)take((size_t)32 * 2304 * 64 * 2);
  ushort_t* Og   = (ushort_t*)take((size_t)4096 * 1024 * 2);
  ushort_t* OUTb = (ushort_t*)take((size_t)4096 * 1024 * 2);
  ushort_t* GLb  = (ushort_t*)take((size_t)4096 * 1024 * 2);
  float* kgm     = (float*)take(2048 * 4);
  float* g2      = (float*)take(2048 * 4);

  k_cvt_all<<<11776, 256, 0, stream>>>(x, kg, Wq, Wk, Wv, Wkk, Wkv, Wo, Wg,
                                       xh, kgh, WB1, WB2, WB3);
  k_kgmean<<<8, 256, 0, stream>>>(kg, kgm);
  k_g2<<<512, 256, 0, stream>>>(kgm, Wg, bg, g2);

  k_gemm<0><<<dim3(32, 24), 256, 0, stream>>>(xh, WB1, bq, bk, bv, nullptr, Qg, Kaug, Vt);
  k_gemm<1><<<dim3(4, 16), 256, 0, stream>>>(kgh, WB2, bkk, bkv, nullptr, nullptr, nullptr, Kaug, Vt);
  k_attn<<<dim3(16, 32), 256, 0, stream>>>(Qg, Kaug, Vt, Og);
  k_gemm<2><<<dim3(32, 16), 256, 0, stream>>>(Og, WB3, bo, nullptr, nullptr, g2, OUTb, GLb, nullptr);
  k_final<<<4096, 256, 0, stream>>>(x, OUTb, GLb, y);
}

// Round 3
// 227.976 us; speedup vs baseline: 1.2806x; 1.1521x over previous
//
#include <hip/hip_runtime.h>
#include <stdint.h>

typedef unsigned short ushort_t;
typedef __attribute__((ext_vector_type(8))) short short8;
typedef __attribute__((ext_vector_type(4))) short short4v;
typedef __attribute__((ext_vector_type(4))) float f32x4;
typedef __attribute__((ext_vector_type(4))) unsigned uintx4;

#define DEV static __device__ __forceinline__

DEV unsigned short f2bf(float f) {
  unsigned u = __builtin_bit_cast(unsigned, f);
  u += 0x7fffu + ((u >> 16) & 1u);
  return (unsigned short)(u >> 16);
}
DEV float bf2f(unsigned short b) {
  return __builtin_bit_cast(float, (unsigned)b << 16);
}

DEV void gl16(const void* g, void* l) {
  __builtin_amdgcn_global_load_lds(
      (__attribute__((address_space(1))) char*)(unsigned long long)g,
      (__attribute__((address_space(3))) char*)(unsigned)(unsigned long long)l,
      16, 0, 0);
}

DEV f32x4 mfma_bf16(short8 a, short8 b, f32x4 c) {
  return __builtin_amdgcn_mfma_f32_16x16x32_bf16(a, b, c, 0, 0, 0);
}

DEV unsigned cvtpk(float lo, float hi) {
  unsigned r;
  asm("v_cvt_pk_bf16_f32 %0, %1, %2" : "=v"(r) : "v"(lo), "v"(hi));
  return r;
}
// after: a = [a.lo32, b.lo32] per-half combine then 16-group interleave (see derivation)
DEV void swap_net(unsigned& a, unsigned& b) {
  asm("v_permlane32_swap_b32 %0, %1" : "+v"(a), "+v"(b));
  asm("v_permlane16_swap_b32 %0, %1" : "+v"(a), "+v"(b));
}
DEV float redmax4(float x) {
  unsigned a = __builtin_bit_cast(unsigned, x), b = a;
  asm("v_permlane16_swap_b32 %0, %1" : "+v"(a), "+v"(b));
  float y = fmaxf(__builtin_bit_cast(float, a), __builtin_bit_cast(float, b));
  unsigned c = __builtin_bit_cast(unsigned, y), d = c;
  asm("v_permlane32_swap_b32 %0, %1" : "+v"(c), "+v"(d));
  return fmaxf(__builtin_bit_cast(float, c), __builtin_bit_cast(float, d));
}
DEV float redsum4(float x) {
  unsigned a = __builtin_bit_cast(unsigned, x), b = a;
  asm("v_permlane16_swap_b32 %0, %1" : "+v"(a), "+v"(b));
  float y = __builtin_bit_cast(float, a) + __builtin_bit_cast(float, b);
  unsigned c = __builtin_bit_cast(unsigned, y), d = c;
  asm("v_permlane32_swap_b32 %0, %1" : "+v"(c), "+v"(d));
  return __builtin_bit_cast(float, c) + __builtin_bit_cast(float, d);
}
DEV float lanebcast(float v, int srclane) {
  return __builtin_bit_cast(float,
      __builtin_amdgcn_ds_bpermute(srclane * 4, __builtin_bit_cast(int, v)));
}

// ---------------- consolidated converts ----------------
__global__ __launch_bounds__(256) void k_cvt_all(
    const float* __restrict__ x, const float* __restrict__ kg,
    const float* __restrict__ Wq, const float* __restrict__ Wk, const float* __restrict__ Wv,
    const float* __restrict__ Wkk, const float* __restrict__ Wkv,
    const float* __restrict__ Wo, const float* __restrict__ Wg,
    ushort_t* __restrict__ xh, ushort_t* __restrict__ kgh,
    ushort_t* __restrict__ WB1, ushort_t* __restrict__ WB2, ushort_t* __restrict__ WB3) {
  const int b = blockIdx.x;
  if (b >= 10752) {
    const int i = (b - 10752) * 256 + threadIdx.x;
    const int r = i >> 8, c = (i & 255) * 4;
    const float4 v = *(const float4*)(Wg + (size_t)r * 2048 + c);
    short4v o;
    o.x = (short)f2bf(v.x); o.y = (short)f2bf(v.y); o.z = (short)f2bf(v.z); o.w = (short)f2bf(v.w);
    *(short4v*)(WB3 + 1048576 + (size_t)r * 1024 + c) = o;
    return;
  }
  const float* src;
  ushort_t* dst;
  int off;
  if (b < 4096)       { src = x;   dst = xh;            off = b; }
  else if (b < 4608)  { src = kg;  dst = kgh;           off = b - 4096; }
  else if (b < 5632)  { src = Wq;  dst = WB1;           off = b - 4608; }
  else if (b < 6656)  { src = Wk;  dst = WB1 + 1048576; off = b - 5632; }
  else if (b < 7680)  { src = Wv;  dst = WB1 + 2097152; off = b - 6656; }
  else if (b < 8704)  { src = Wkk; dst = WB2;           off = b - 7680; }
  else if (b < 9728)  { src = Wkv; dst = WB2 + 1048576; off = b - 8704; }
  else                { src = Wo;  dst = WB3;           off = b - 9728; }
  const int i = off * 1024 + threadIdx.x * 4;
  const float4 v = *(const float4*)(src + i);
  short4v o;
  o.x = (short)f2bf(v.x); o.y = (short)f2bf(v.y); o.z = (short)f2bf(v.z); o.w = (short)f2bf(v.w);
  *(short4v*)(dst + i) = o;
}

__global__ __launch_bounds__(256) void k_kgmean(const float* __restrict__ kg, float* __restrict__ out) {
  const int i = blockIdx.x * 256 + threadIdx.x;
  const int b = i >> 10, d = i & 1023;
  float s = 0.f;
  #pragma unroll 4
  for (int e = 0; e < 256; e++) s += kg[((size_t)b * 256 + e) * 1024 + d];
  out[i] = s * (1.0f / 256.0f);
}

__global__ __launch_bounds__(256) void k_g2(const float* __restrict__ kgm, const float* __restrict__ Wg,
                                            const float* __restrict__ bg, float* __restrict__ g2) {
  const int w = threadIdx.x >> 6, l = threadIdx.x & 63;
  const int idx = blockIdx.x * 4 + w;
  const int b = idx >> 10, n = idx & 1023;
  const float* wr = Wg + (size_t)n * 2048 + 1024;
  const float* mb = kgm + b * 1024;
  float s = 0.f;
  #pragma unroll
  for (int j = 0; j < 16; j++) s += mb[j * 64 + l] * wr[j * 64 + l];
  #pragma unroll
  for (int m = 32; m >= 1; m >>= 1) s += __shfl_xor(s, m);
  if (l == 0) g2[idx] = s + bg[n];
}

// ---------------- GEMM: C[M,N] = A[M,1024] * Bw[N,1024]^T, bf16 MFMA ----------------
template <int MODE>
__global__ __launch_bounds__(256) void k_gemm(
    const ushort_t* __restrict__ A, const ushort_t* __restrict__ Bw,
    const float* __restrict__ bias0, const float* __restrict__ bias1, const float* __restrict__ bias2,
    const float* __restrict__ g2v,
    ushort_t* __restrict__ o0, ushort_t* __restrict__ o1, ushort_t* __restrict__ o2) {
  __shared__ __align__(16) ushort_t As[2][128 * 32];
  __shared__ __align__(16) ushort_t Bs[2][128 * 32];
  const int tid = threadIdx.x;
  const int w = tid >> 6, l = tid & 63;
  const int wr = w >> 1, wc = w & 1;
  const int fr = l & 15, fg = l >> 4;
  const int m0 = blockIdx.x * 128, n0 = blockIdx.y * 128;
  const int srow = tid >> 2, sseg = tid & 3;
  const ushort_t* ga = A + (size_t)(m0 + srow) * 1024 + sseg * 8;
  const ushort_t* gb = Bw + (size_t)(n0 + srow) * 1024 + sseg * 8;
  f32x4 acc[4][4] = {};

  auto stage = [&](int nb, int kt) {
    char* lA = (char*)&As[nb][0] + w * 1024;
    char* lB = (char*)&Bs[nb][0] + w * 1024;
    const ushort_t* gA = ga + kt * 32;
    const ushort_t* gB = gb + kt * 32;
    gl16(gA, lA);
    gl16(gA + 64 * 1024, lA + 4096);
    gl16(gB, lB);
    gl16(gB + 64 * 1024, lB + 4096);
  };

  stage(0, 0);
  __syncthreads();
  int cur = 0;
  for (int kt = 0; kt < 32; kt++) {
    if (kt < 31) stage(cur ^ 1, kt + 1);
    const short* Ab = (const short*)&As[cur][0];
    const short* Bb = (const short*)&Bs[cur][0];
    short8 af[4], bfr[4];
    #pragma unroll
    for (int i = 0; i < 4; i++) {
      af[i]  = *(const short8*)(Ab + (wr * 64 + i * 16 + fr) * 32 + fg * 8);
      bfr[i] = *(const short8*)(Bb + (wc * 64 + i * 16 + fr) * 32 + fg * 8);
    }
    #pragma unroll
    for (int i = 0; i < 4; i++)
      #pragma unroll
      for (int j = 0; j < 4; j++)
        acc[i][j] = mfma_bf16(af[i], bfr[j], acc[i][j]);
    __syncthreads();
    cur ^= 1;
  }

  const int sec = n0 >> 10;
  #pragma unroll
  for (int i = 0; i < 4; i++) {
    #pragma unroll
    for (int j = 0; j < 4; j++) {
      #pragma unroll
      for (int r = 0; r < 4; r++) {
        const int m = m0 + wr * 64 + i * 16 + fg * 4 + r;
        const int nn = (n0 & 1023) + wc * 64 + j * 16 + fr;
        const int h = nn >> 6, d = nn & 63;
        const float v = acc[i][j][r];
        if constexpr (MODE == 0) {
          const int b = m >> 11, lq = m & 2047;
          if (sec == 0)
            o0[((size_t)(b * 16 + h) * 2048 + lq) * 64 + d] = f2bf((v + bias0[nn]) * 0.18033688f); // 0.125*log2e
          else if (sec == 1)
            o1[((size_t)(b * 16 + h) * 2304 + lq) * 64 + d] = f2bf(v + bias1[nn]);
          else
            o2[((size_t)(b * 16 + h) * 64 + d) * 2304 + lq] = f2bf(v + bias2[nn]);
        } else if constexpr (MODE == 1) {
          const int b = m >> 8, e = m & 255;
          if (sec == 0)
            o1[((size_t)(b * 16 + h) * 2304 + 2048 + e) * 64 + d] = f2bf(v + bias0[nn]);
          else
            o2[((size_t)(b * 16 + h) * 64 + d) * 2304 + 2048 + e] = f2bf(v + bias1[nn]);
        } else {
          const int b = m >> 11;
          if (sec == 0)
            o0[(size_t)m * 1024 + nn] = f2bf(v + bias0[nn]);
          else
            o1[(size_t)m * 1024 + nn] = f2bf(v + g2v[b * 1024 + nn]);
        }
      }
    }
  }
}

// ---------------- flash attention (swapped QK^T, in-register P) ----------------
// Qg [bh][2048][64] (pre-scaled by 0.125*log2e), Kg [bh][2304][64], Vtg [bh][64][2304],
// Og [b*2048][1024] (all bf16). exp in base-2 domain.
__global__ __launch_bounds__(256, 2) void k_attn(
    const ushort_t* __restrict__ Qg, const ushort_t* __restrict__ Kg,
    const ushort_t* __restrict__ Vtg, ushort_t* __restrict__ Og) {
  __shared__ __align__(16) ushort_t Ks[2][64 * 64];   // XOR-swizzled [kv][d]
  __shared__ __align__(16) ushort_t Vs[2][64 * 64];   // XOR-swizzled [d][kv]
  const int tid = threadIdx.x;
  const int w = tid >> 6, l = tid & 63;
  const int fr = l & 15, fg = l >> 4;
  const int bh = blockIdx.y;
  const int q0 = blockIdx.x * 128 + w * 32;

  // Q fragments (B-operand): qf[i][c] = Q[q0 + i*16 + fr][c*32 + fg*8 ..+8]
  short8 qf[2][2];
  #pragma unroll
  for (int i = 0; i < 2; i++) {
    const short* qrow = (const short*)(Qg + ((size_t)bh * 2048 + q0 + i * 16 + fr) * 64);
    qf[i][0] = *(const short8*)(qrow + fg * 8);
    qf[i][1] = *(const short8*)(qrow + 32 + fg * 8);
  }

  f32x4 o[2][4] = {};            // o[i][dt]: rows q=i*16+fg*4+r, cols dv=dt*16+fr
  float mrun[2], lpart[2];       // per-lane state in the fr(q) domain
  mrun[0] = mrun[1] = -1.0e30f;
  lpart[0] = lpart[1] = 0.f;

  const int srow = tid >> 2, sseg = tid & 3;
  const ushort_t* kgb = Kg + ((size_t)bh * 2304 + srow) * 64 + sseg * 16;
  const ushort_t* vgb = Vtg + ((size_t)bh * 64 + srow) * 2304 + sseg * 16;
  const int sdst = srow * 128 + sseg * 32;
  const int sswz = (srow & 7) << 4;

  // prologue: stage tile 0
  {
    const short8 ka = *(const short8*)(kgb);
    const short8 kb = *(const short8*)(kgb + 8);
    const short8 va = *(const short8*)(vgb);
    const short8 vb = *(const short8*)(vgb + 8);
    *(short8*)((char*)&Ks[0][0] + (sdst ^ sswz)) = ka;
    *(short8*)((char*)&Ks[0][0] + ((sdst + 16) ^ sswz)) = kb;
    *(short8*)((char*)&Vs[0][0] + (sdst ^ sswz)) = va;
    *(short8*)((char*)&Vs[0][0] + ((sdst + 16) ^ sswz)) = vb;
  }

  const int rswz = (fr & 7) << 4;

  for (int mt = 0; mt < 36; mt++) {
    __syncthreads();

    // prefetch tile mt+1 into registers (hides under compute)
    short8 krn0, krn1, vrn0, vrn1;
    if (mt < 35) {
      const size_t ko = (size_t)(mt + 1) * 4096;
      krn0 = *(const short8*)(kgb + ko);
      krn1 = *(const short8*)(kgb + ko + 8);
      vrn0 = *(const short8*)(vgb + (mt + 1) * 64);
      vrn1 = *(const short8*)(vgb + (mt + 1) * 64 + 8);
    }

    const char* Kb = (const char*)&Ks[mt & 1][0];
    const char* Vb = (const char*)&Vs[mt & 1][0];

    // swapped QK^T: s[i][t] = S^T tile -> lane: q=fr, kv = t*16 + fg*4 + r
    f32x4 s[2][4];
    #pragma unroll
    for (int t = 0; t < 4; t++) {
      const int rb = (t * 16 + fr) * 128 + fg * 16;
      const short8 k0 = *(const short8*)(Kb + (rb ^ rswz));
      const short8 k1 = *(const short8*)(Kb + ((rb + 64) ^ rswz));
      #pragma unroll
      for (int i = 0; i < 2; i++) {
        f32x4 z = {};
        z = mfma_bf16(k0, qf[i][0], z);
        z = mfma_bf16(k1, qf[i][1], z);
        s[i][t] = z;
      }
    }

    // online softmax (base-2), per-lane scalar state (q = fr)
    float mx[2];
    #pragma unroll
    for (int i = 0; i < 2; i++) {
      float m = s[i][0][0];
      #pragma unroll
      for (int t = 0; t < 4; t++)
        #pragma unroll
        for (int r = 0; r < 4; r++) m = fmaxf(m, s[i][t][r]);
      mx[i] = redmax4(m);
    }
    const float need = fmaxf(mx[0] - mrun[0], mx[1] - mrun[1]);
    if (__any(need > 11.5416f)) {  // 8 nats in log2 domain
      #pragma unroll
      for (int i = 0; i < 2; i++) {
        const float mn = fmaxf(mrun[i], mx[i]);
        const float al = exp2f(mrun[i] - mn);
        mrun[i] = mn;
        lpart[i] *= al;
        float ab[4];
        #pragma unroll
        for (int r = 0; r < 4; r++) ab[r] = lanebcast(al, fg * 4 + r);
        #pragma unroll
        for (int dt = 0; dt < 4; dt++)
          #pragma unroll
          for (int r = 0; r < 4; r++) o[i][dt][r] *= ab[r];
      }
    }
    #pragma unroll
    for (int i = 0; i < 2; i++) {
      float sm = 0.f;
      #pragma unroll
      for (int t = 0; t < 4; t++) {
        #pragma unroll
        for (int r = 0; r < 4; r++) {
          const float p = exp2f(s[i][t][r] - mrun[i]);
          s[i][t][r] = p;
          sm += p;
        }
      }
      lpart[i] += sm;
    }

    // PV: assemble P A-frags in-register (cvt_pk + permlane swap network), no LDS
    #pragma unroll
    for (int c = 0; c < 2; c++) {
      short8 pf[2];
      #pragma unroll
      for (int i = 0; i < 2; i++) {
        unsigned a0 = cvtpk(s[i][2 * c][0], s[i][2 * c][1]);      // kv t0: fg*4+0,1
        unsigned b0 = cvtpk(s[i][2 * c + 1][0], s[i][2 * c + 1][1]);
        unsigned a1 = cvtpk(s[i][2 * c][2], s[i][2 * c][3]);      // kv t0: fg*4+2,3
        unsigned b1 = cvtpk(s[i][2 * c + 1][2], s[i][2 * c + 1][3]);
        swap_net(a0, b0);  // a0 -> frag elems 0,1 ; b0 -> elems 4,5
        swap_net(a1, b1);  // a1 -> elems 2,3 ; b1 -> elems 6,7
        uintx4 u;
        u.x = a0; u.y = a1; u.z = b0; u.w = b1;
        pf[i] = __builtin_bit_cast(short8, u);
      }
      #pragma unroll
      for (int dt = 0; dt < 4; dt++) {
        const int vb = ((dt * 16 + fr) * 128) + fg * 16 + c * 64;
        const short8 vf = *(const short8*)(Vb + (vb ^ rswz));
        o[0][dt] = mfma_bf16(pf[0], vf, o[0][dt]);
        o[1][dt] = mfma_bf16(pf[1], vf, o[1][dt]);
      }
    }

    // stage tile mt+1 into the other buffer
    if (mt < 35) {
      char* Kd = (char*)&Ks[(mt + 1) & 1][0];
      char* Vd = (char*)&Vs[(mt + 1) & 1][0];
      *(short8*)(Kd + (sdst ^ sswz)) = krn0;
      *(short8*)(Kd + ((sdst + 16) ^ sswz)) = krn1;
      *(short8*)(Vd + (sdst ^ sswz)) = vrn0;
      *(short8*)(Vd + ((sdst + 16) ^ sswz)) = vrn1;
    }
  }

  const int b = bh >> 4, h = bh & 15;
  #pragma unroll
  for (int i = 0; i < 2; i++) {
    const float linv = 1.0f / redsum4(lpart[i]);
    float lr[4];
    #pragma unroll
    for (int r = 0; r < 4; r++) lr[r] = lanebcast(linv, fg * 4 + r);
    #pragma unroll
    for (int r = 0; r < 4; r++) {
      const int q = q0 + i * 16 + fg * 4 + r;
      ushort_t* orow = Og + ((size_t)b * 2048 + q) * 1024 + h * 64;
      #pragma unroll
      for (int dt = 0; dt < 4; dt++) orow[dt * 16 + fr] = f2bf(o[i][dt][r] * lr[r]);
    }
  }
}

// ---------------- final mix ----------------
__global__ __launch_bounds__(256) void k_final(const float* __restrict__ x,
                                               const ushort_t* __restrict__ OUT,
                                               const ushort_t* __restrict__ GL,
                                               float* __restrict__ y) {
  const int i = (blockIdx.x * 256 + threadIdx.x) * 4;
  const float4 xv = *(const float4*)(x + i);
  const short4v ov = *(const short4v*)((const short*)OUT + i);
  const short4v gv = *(const short4v*)((const short*)GL + i);
  float4 r;
  {
    const float o0 = bf2f((unsigned short)ov.x);
    const float g0 = 1.f / (1.f + __expf(-bf2f((unsigned short)gv.x)));
    r.x = xv.x + g0 * (o0 - xv.x);
  }
  {
    const float o1 = bf2f((unsigned short)ov.y);
    const float g1 = 1.f / (1.f + __expf(-bf2f((unsigned short)gv.y)));
    r.y = xv.y + g1 * (o1 - xv.y);
  }
  {
    const float o2 = bf2f((unsigned short)ov.z);
    const float g2 = 1.f / (1.f + __expf(-bf2f((unsigned short)gv.z)));
    r.z = xv.z + g2 * (o2 - xv.z);
  }
  {
    const float o3 = bf2f((unsigned short)ov.w);
    const float g3 = 1.f / (1.f + __expf(-bf2f((unsigned short)gv.w)));
    r.w = xv.w + g3 * (o3 - xv.w);
  }
  *(float4*)(y + i) = r;
}

extern "C" void kernel_launch(void* const* d_in, const int* in_sizes, int n_in,
                              void* d_out, int out_size, void* d_ws, size_t ws_size,
                              hipStream_t stream) {
  (void)in_sizes; (void)n_in; (void)out_size; (void)ws_size;
  const float* x   = (const float*)d_in[0];
  const float* kg  = (const float*)d_in[1];
  const float* Wq  = (const float*)d_in[2];
  const float* bq  = (const float*)d_in[3];
  const float* Wk  = (const float*)d_in[4];
  const float* bk  = (const float*)d_in[5];
  const float* Wv  = (const float*)d_in[6];
  const float* bv  = (const float*)d_in[7];
  const float* Wkk = (const float*)d_in[8];
  const float* bkk = (const float*)d_in[9];
  const float* Wkv = (const float*)d_in[10];
  const float* bkv = (const float*)d_in[11];
  const float* Wo  = (const float*)d_in[12];
  const float* bo  = (const float*)d_in[13];
  const float* Wg  = (const float*)d_in[14];
  const float* bg  = (const float*)d_in[15];
  float* y = (float*)d_out;

  char* ws = (char*)d_ws;
  size_t off = 0;
  auto take = [&](size_t bytes) {
    char* p = ws + off;
    off += (bytes + 255) & ~(size_t)255;
    return p;
  };
  ushort_t* xh   = (ushort_t*)take((size_t)4096 * 1024 * 2);
  ushort_t* kgh  = (ushort_t*)take((size_t)512 * 1024 * 2);
  ushort_t* WB1  = (ushort_t*)take((size_t)3072 * 1024 * 2);
  ushort_t* WB2  = (ushort_t*)take((size_t)2048 * 1024 * 2);
  ushort_t* WB3  = (ushort_t*)take((size_t)2048 * 1024 * 2);
  ushort_t* Qg   = (ushort_t*)take((size_t)32 * 2048 * 64 * 2);
  ushort_t* Kaug = (ushort_t*)take((size_t)32 * 2304 * 64 * 2);
  ushort_t* Vt   = (ushort_t*)take((size_t)32 * 2304 * 64 * 2);
  ushort_t* Og   = (ushort_t*)take((size_t)4096 * 1024 * 2);
  ushort_t* OUTb = (ushort_t*)take((size_t)4096 * 1024 * 2);
  ushort_t* GLb  = (ushort_t*)take((size_t)4096 * 1024 * 2);
  float* kgm     = (float*)take(2048 * 4);
  float* g2      = (float*)take(2048 * 4);

  k_cvt_all<<<11776, 256, 0, stream>>>(x, kg, Wq, Wk, Wv, Wkk, Wkv, Wo, Wg,
                                       xh, kgh, WB1, WB2, WB3);
  k_kgmean<<<8, 256, 0, stream>>>(kg, kgm);
  k_g2<<<512, 256, 0, stream>>>(kgm, Wg, bg, g2);

  k_gemm<0><<<dim3(32, 24), 256, 0, stream>>>(xh, WB1, bq, bk, bv, nullptr, Qg, Kaug, Vt);
  k_gemm<1><<<dim3(4, 16), 256, 0, stream>>>(kgh, WB2, bkk, bkv, nullptr, nullptr, nullptr, Kaug, Vt);
  k_attn<<<dim3(16, 32), 256, 0, stream>>>(Qg, Kaug, Vt, Og);
  k_gemm<2><<<dim3(32, 16), 256, 0, stream>>>(Og, WB3, bo, nullptr, nullptr, g2, OUTb, GLb, nullptr);
  k_final<<<4096, 256, 0, stream>>>(x, OUTb, GLb, y);
}

// Round 4
// 216.149 us; speedup vs baseline: 1.3506x; 1.0547x over previous
//
#include <hip/hip_runtime.h>
#include <stdint.h>

typedef unsigned short ushort_t;
typedef __attribute__((ext_vector_type(8))) short short8;
typedef __attribute__((ext_vector_type(4))) short short4v;
typedef __attribute__((ext_vector_type(4))) float f32x4;
typedef __attribute__((ext_vector_type(4))) unsigned uintx4;

#define DEV static __device__ __forceinline__

DEV unsigned short f2bf(float f) {
  unsigned u = __builtin_bit_cast(unsigned, f);
  u += 0x7fffu + ((u >> 16) & 1u);
  return (unsigned short)(u >> 16);
}
DEV float bf2f(unsigned short b) {
  return __builtin_bit_cast(float, (unsigned)b << 16);
}

DEV void gl16(const void* g, void* l) {
  __builtin_amdgcn_global_load_lds(
      (__attribute__((address_space(1))) char*)(unsigned long long)g,
      (__attribute__((address_space(3))) char*)(unsigned)(unsigned long long)l,
      16, 0, 0);
}

DEV f32x4 mfma_bf16(short8 a, short8 b, f32x4 c) {
  return __builtin_amdgcn_mfma_f32_16x16x32_bf16(a, b, c, 0, 0, 0);
}

DEV unsigned cvtpk(float lo, float hi) {
  unsigned r;
  asm("v_cvt_pk_bf16_f32 %0, %1, %2" : "=v"(r) : "v"(lo), "v"(hi));
  return r;
}
DEV void swap_net(unsigned& a, unsigned& b) {
  asm("v_permlane32_swap_b32 %0, %1" : "+v"(a), "+v"(b));
  asm("v_permlane16_swap_b32 %0, %1" : "+v"(a), "+v"(b));
}
DEV float redmax4(float x) {
  unsigned a = __builtin_bit_cast(unsigned, x), b = a;
  asm("v_permlane16_swap_b32 %0, %1" : "+v"(a), "+v"(b));
  float y = fmaxf(__builtin_bit_cast(float, a), __builtin_bit_cast(float, b));
  unsigned c = __builtin_bit_cast(unsigned, y), d = c;
  asm("v_permlane32_swap_b32 %0, %1" : "+v"(c), "+v"(d));
  return fmaxf(__builtin_bit_cast(float, c), __builtin_bit_cast(float, d));
}
DEV float lanebcast(float v, int srclane) {
  return __builtin_bit_cast(float,
      __builtin_amdgcn_ds_bpermute(srclane * 4, __builtin_bit_cast(int, v)));
}

// ---------------- consolidated converts ----------------
__global__ __launch_bounds__(256) void k_cvt_all(
    const float* __restrict__ x, const float* __restrict__ kg,
    const float* __restrict__ Wq, const float* __restrict__ Wk, const float* __restrict__ Wv,
    const float* __restrict__ Wkk, const float* __restrict__ Wkv,
    const float* __restrict__ Wo, const float* __restrict__ Wg,
    ushort_t* __restrict__ xh, ushort_t* __restrict__ kgh,
    ushort_t* __restrict__ WB1, ushort_t* __restrict__ WB2, ushort_t* __restrict__ WB3) {
  const int b = blockIdx.x;
  if (b >= 10752) {
    const int i = (b - 10752) * 256 + threadIdx.x;
    const int r = i >> 8, c = (i & 255) * 4;
    const float4 v = *(const float4*)(Wg + (size_t)r * 2048 + c);
    short4v o;
    o.x = (short)f2bf(v.x); o.y = (short)f2bf(v.y); o.z = (short)f2bf(v.z); o.w = (short)f2bf(v.w);
    *(short4v*)(WB3 + 1048576 + (size_t)r * 1024 + c) = o;
    return;
  }
  const float* src;
  ushort_t* dst;
  int off;
  if (b < 4096)       { src = x;   dst = xh;            off = b; }
  else if (b < 4608)  { src = kg;  dst = kgh;           off = b - 4096; }
  else if (b < 5632)  { src = Wq;  dst = WB1;           off = b - 4608; }
  else if (b < 6656)  { src = Wk;  dst = WB1 + 1048576; off = b - 5632; }
  else if (b < 7680)  { src = Wv;  dst = WB1 + 2097152; off = b - 6656; }
  else if (b < 8704)  { src = Wkk; dst = WB2;           off = b - 7680; }
  else if (b < 9728)  { src = Wkv; dst = WB2 + 1048576; off = b - 8704; }
  else                { src = Wo;  dst = WB3;           off = b - 9728; }
  const int i = off * 1024 + threadIdx.x * 4;
  const float4 v = *(const float4*)(src + i);
  short4v o;
  o.x = (short)f2bf(v.x); o.y = (short)f2bf(v.y); o.z = (short)f2bf(v.z); o.w = (short)f2bf(v.w);
  *(short4v*)(dst + i) = o;
}

__global__ __launch_bounds__(256) void k_kgmean(const float* __restrict__ kg, float* __restrict__ out) {
  const int i = blockIdx.x * 256 + threadIdx.x;
  const int b = i >> 10, d = i & 1023;
  float s = 0.f;
  #pragma unroll 4
  for (int e = 0; e < 256; e++) s += kg[((size_t)b * 256 + e) * 1024 + d];
  out[i] = s * (1.0f / 256.0f);
}

__global__ __launch_bounds__(256) void k_g2(const float* __restrict__ kgm, const float* __restrict__ Wg,
                                            const float* __restrict__ bg, float* __restrict__ g2) {
  const int w = threadIdx.x >> 6, l = threadIdx.x & 63;
  const int idx = blockIdx.x * 4 + w;
  const int b = idx >> 10, n = idx & 1023;
  const float* wr = Wg + (size_t)n * 2048 + 1024;
  const float* mb = kgm + b * 1024;
  float s = 0.f;
  #pragma unroll
  for (int j = 0; j < 16; j++) s += mb[j * 64 + l] * wr[j * 64 + l];
  #pragma unroll
  for (int m = 32; m >= 1; m >>= 1) s += __shfl_xor(s, m);
  if (l == 0) g2[idx] = s + bg[n];
}

// ---------------- GEMM: C[M,N] = A[M,1024] * Bw[N,1024]^T, bf16 MFMA ----------------
template <int MODE>
__global__ __launch_bounds__(256) void k_gemm(
    const ushort_t* __restrict__ A, const ushort_t* __restrict__ Bw,
    const float* __restrict__ bias0, const float* __restrict__ bias1, const float* __restrict__ bias2,
    const float* __restrict__ g2v,
    ushort_t* __restrict__ o0, ushort_t* __restrict__ o1, ushort_t* __restrict__ o2) {
  __shared__ __align__(16) ushort_t As[2][128 * 32];
  __shared__ __align__(16) ushort_t Bs[2][128 * 32];
  const int tid = threadIdx.x;
  const int w = tid >> 6, l = tid & 63;
  const int wr = w >> 1, wc = w & 1;
  const int fr = l & 15, fg = l >> 4;
  const int m0 = blockIdx.x * 128, n0 = blockIdx.y * 128;
  const int srow = tid >> 2, sseg = tid & 3;
  const ushort_t* ga = A + (size_t)(m0 + srow) * 1024 + sseg * 8;
  const ushort_t* gb = Bw + (size_t)(n0 + srow) * 1024 + sseg * 8;
  f32x4 acc[4][4] = {};

  auto stage = [&](int nb, int kt) {
    char* lA = (char*)&As[nb][0] + w * 1024;
    char* lB = (char*)&Bs[nb][0] + w * 1024;
    const ushort_t* gA = ga + kt * 32;
    const ushort_t* gB = gb + kt * 32;
    gl16(gA, lA);
    gl16(gA + 64 * 1024, lA + 4096);
    gl16(gB, lB);
    gl16(gB + 64 * 1024, lB + 4096);
  };

  stage(0, 0);
  __syncthreads();
  int cur = 0;
  for (int kt = 0; kt < 32; kt++) {
    if (kt < 31) stage(cur ^ 1, kt + 1);
    const short* Ab = (const short*)&As[cur][0];
    const short* Bb = (const short*)&Bs[cur][0];
    short8 af[4], bfr[4];
    #pragma unroll
    for (int i = 0; i < 4; i++) {
      af[i]  = *(const short8*)(Ab + (wr * 64 + i * 16 + fr) * 32 + fg * 8);
      bfr[i] = *(const short8*)(Bb + (wc * 64 + i * 16 + fr) * 32 + fg * 8);
    }
    #pragma unroll
    for (int i = 0; i < 4; i++)
      #pragma unroll
      for (int j = 0; j < 4; j++)
        acc[i][j] = mfma_bf16(af[i], bfr[j], acc[i][j]);
    __syncthreads();
    cur ^= 1;
  }

  const int sec = n0 >> 10;
  #pragma unroll
  for (int i = 0; i < 4; i++) {
    #pragma unroll
    for (int j = 0; j < 4; j++) {
      #pragma unroll
      for (int r = 0; r < 4; r++) {
        const int m = m0 + wr * 64 + i * 16 + fg * 4 + r;
        const int nn = (n0 & 1023) + wc * 64 + j * 16 + fr;
        const int h = nn >> 6, d = nn & 63;
        const float v = acc[i][j][r];
        if constexpr (MODE == 0) {
          const int b = m >> 11, lq = m & 2047;
          if (sec == 0)
            o0[((size_t)(b * 16 + h) * 2048 + lq) * 64 + d] = f2bf((v + bias0[nn]) * 0.18033688f); // 0.125*log2e
          else if (sec == 1)
            o1[((size_t)(b * 16 + h) * 2304 + lq) * 64 + d] = f2bf(v + bias1[nn]);
          else
            o2[((size_t)(b * 16 + h) * 64 + d) * 2304 + lq] = f2bf(v + bias2[nn]);
        } else if constexpr (MODE == 1) {
          const int b = m >> 8, e = m & 255;
          if (sec == 0)
            o1[((size_t)(b * 16 + h) * 2304 + 2048 + e) * 64 + d] = f2bf(v + bias0[nn]);
          else
            o2[((size_t)(b * 16 + h) * 64 + d) * 2304 + 2048 + e] = f2bf(v + bias1[nn]);
        } else {
          const int b = m >> 11;
          if (sec == 0)
            o0[(size_t)m * 1024 + nn] = f2bf(v + bias0[nn]);
          else
            o1[(size_t)m * 1024 + nn] = f2bf(v + g2v[b * 1024 + nn]);
        }
      }
    }
  }
}

// ---------------- flash attention (QBLK=64, XCD swizzle, in-register P + l) -------
// Qg [bh][2048][64] (pre-scaled by 0.125*log2e), Kg [bh][2304][64], Vtg [bh][64][2304],
// Og [b*2048][1024] (all bf16). exp in base-2 domain.
__global__ __launch_bounds__(256, 4) void k_attn(
    const ushort_t* __restrict__ Qg, const ushort_t* __restrict__ Kg,
    const ushort_t* __restrict__ Vtg, ushort_t* __restrict__ Og) {
  __shared__ __align__(16) ushort_t Ks[2][64 * 64];   // XOR-swizzled [kv][d]
  __shared__ __align__(16) ushort_t Vs[2][64 * 64];   // XOR-swizzled [d][kv]
  const int tid = threadIdx.x;
  const int w = tid >> 6, l = tid & 63;
  const int fr = l & 15, fg = l >> 4;

  // XCD-aware swizzle: concentrate each bh's q-blocks on one XCD (round-robin model)
  const int id = blockIdx.y * gridDim.x + blockIdx.x;      // 0..1023
  const int bh = (id & 7) * 4 + ((id >> 3) >> 5);
  const int q0 = ((id >> 3) & 31) * 64 + w * 16;

  // Q fragments (B-operand): qf[c] = Q[q0 + fr][c*32 + fg*8 ..+8]
  short8 qf[2];
  {
    const short* qrow = (const short*)(Qg + ((size_t)bh * 2048 + q0 + fr) * 64);
    qf[0] = *(const short8*)(qrow + fg * 8);
    qf[1] = *(const short8*)(qrow + 32 + fg * 8);
  }

  constexpr short ONE = 0x3F80;  // bf16 1.0
  const short8 ones = {ONE, ONE, ONE, ONE, ONE, ONE, ONE, ONE};

  f32x4 o[4] = {};     // o[dt]: rows q=fg*4+r, cols dv=dt*16+fr
  f32x4 lacc = {};     // same layout; every column holds the row-sum
  float mrun = -1.0e30f;  // per-lane, q = fr domain

  const int srow = tid >> 2, sseg = tid & 3;
  const ushort_t* kgb = Kg + ((size_t)bh * 2304 + srow) * 64 + sseg * 16;
  const ushort_t* vgb = Vtg + ((size_t)bh * 64 + srow) * 2304 + sseg * 16;
  const int sdst = srow * 128 + sseg * 32;
  const int sswz = (srow & 7) << 4;

  // prologue: stage tile 0
  {
    const short8 ka = *(const short8*)(kgb);
    const short8 kb = *(const short8*)(kgb + 8);
    const short8 va = *(const short8*)(vgb);
    const short8 vb = *(const short8*)(vgb + 8);
    *(short8*)((char*)&Ks[0][0] + (sdst ^ sswz)) = ka;
    *(short8*)((char*)&Ks[0][0] + ((sdst + 16) ^ sswz)) = kb;
    *(short8*)((char*)&Vs[0][0] + (sdst ^ sswz)) = va;
    *(short8*)((char*)&Vs[0][0] + ((sdst + 16) ^ sswz)) = vb;
  }

  const int rswz = (fr & 7) << 4;

  for (int mt = 0; mt < 36; mt++) {
    __syncthreads();

    // prefetch tile mt+1 into registers (hides under compute)
    short8 krn0, krn1, vrn0, vrn1;
    if (mt < 35) {
      const size_t ko = (size_t)(mt + 1) * 4096;
      krn0 = *(const short8*)(kgb + ko);
      krn1 = *(const short8*)(kgb + ko + 8);
      vrn0 = *(const short8*)(vgb + (mt + 1) * 64);
      vrn1 = *(const short8*)(vgb + (mt + 1) * 64 + 8);
    }

    const char* Kb = (const char*)&Ks[mt & 1][0];
    const char* Vb = (const char*)&Vs[mt & 1][0];

    // swapped QK^T: lane holds S^T: q=fr, kv = t*16 + fg*4 + r
    f32x4 s[4];
    #pragma unroll
    for (int t = 0; t < 4; t++) {
      const int rb = (t * 16 + fr) * 128 + fg * 16;
      const short8 k0 = *(const short8*)(Kb + (rb ^ rswz));
      const short8 k1 = *(const short8*)(Kb + ((rb + 64) ^ rswz));
      f32x4 z = {};
      z = mfma_bf16(k0, qf[0], z);
      z = mfma_bf16(k1, qf[1], z);
      s[t] = z;
    }

    // online softmax (base-2), per-lane scalar running max (q = fr)
    float m = s[0][0];
    #pragma unroll
    for (int t = 0; t < 4; t++)
      #pragma unroll
      for (int r = 0; r < 4; r++) m = fmaxf(m, s[t][r]);
    const float mx = redmax4(m);
    if (__any(mx - mrun > 11.5416f)) {  // 8 nats in log2 domain
      const float mn = fmaxf(mrun, mx);
      const float al = __builtin_amdgcn_exp2f(mrun - mn);
      mrun = mn;
      float ab[4];
      #pragma unroll
      for (int r = 0; r < 4; r++) ab[r] = lanebcast(al, fg * 4 + r);
      #pragma unroll
      for (int r = 0; r < 4; r++) {
        lacc[r] *= ab[r];
        #pragma unroll
        for (int dt = 0; dt < 4; dt++) o[dt][r] *= ab[r];
      }
    }
    #pragma unroll
    for (int t = 0; t < 4; t++)
      #pragma unroll
      for (int r = 0; r < 4; r++)
        s[t][r] = __builtin_amdgcn_exp2f(s[t][r] - mrun);

    // PV: assemble P A-frags in-register; l-sum via ones-MFMA (lands in C-layout)
    #pragma unroll
    for (int c = 0; c < 2; c++) {
      unsigned a0 = cvtpk(s[2 * c][0], s[2 * c][1]);
      unsigned b0 = cvtpk(s[2 * c + 1][0], s[2 * c + 1][1]);
      unsigned a1 = cvtpk(s[2 * c][2], s[2 * c][3]);
      unsigned b1 = cvtpk(s[2 * c + 1][2], s[2 * c + 1][3]);
      swap_net(a0, b0);
      swap_net(a1, b1);
      uintx4 u;
      u.x = a0; u.y = a1; u.z = b0; u.w = b1;
      const short8 pf = __builtin_bit_cast(short8, u);
      lacc = mfma_bf16(pf, ones, lacc);
      #pragma unroll
      for (int dt = 0; dt < 4; dt++) {
        const int vb = ((dt * 16 + fr) * 128) + fg * 16 + c * 64;
        const short8 vf = *(const short8*)(Vb + (vb ^ rswz));
        o[dt] = mfma_bf16(pf, vf, o[dt]);
      }
    }

    // stage tile mt+1 into the other buffer
    if (mt < 35) {
      char* Kd = (char*)&Ks[(mt + 1) & 1][0];
      char* Vd = (char*)&Vs[(mt + 1) & 1][0];
      *(short8*)(Kd + (sdst ^ sswz)) = krn0;
      *(short8*)(Kd + ((sdst + 16) ^ sswz)) = krn1;
      *(short8*)(Vd + (sdst ^ sswz)) = vrn0;
      *(short8*)(Vd + ((sdst + 16) ^ sswz)) = vrn1;
    }
  }

  const int b = bh >> 4, h = bh & 15;
  #pragma unroll
  for (int r = 0; r < 4; r++) {
    const float inv = 1.0f / lacc[r];
    const int q = q0 + fg * 4 + r;
    ushort_t* orow = Og + ((size_t)b * 2048 + q) * 1024 + h * 64;
    #pragma unroll
    for (int dt = 0; dt < 4; dt++) orow[dt * 16 + fr] = f2bf(o[dt][r] * inv);
  }
}

// ---------------- final mix ----------------
__global__ __launch_bounds__(256) void k_final(const float* __restrict__ x,
                                               const ushort_t* __restrict__ OUT,
                                               const ushort_t* __restrict__ GL,
                                               float* __restrict__ y) {
  const int i = (blockIdx.x * 256 + threadIdx.x) * 4;
  const float4 xv = *(const float4*)(x + i);
  const short4v ov = *(const short4v*)((const short*)OUT + i);
  const short4v gv = *(const short4v*)((const short*)GL + i);
  float4 r;
  {
    const float o0 = bf2f((unsigned short)ov.x);
    const float g0 = 1.f / (1.f + __expf(-bf2f((unsigned short)gv.x)));
    r.x = xv.x + g0 * (o0 - xv.x);
  }
  {
    const float o1 = bf2f((unsigned short)ov.y);
    const float g1 = 1.f / (1.f + __expf(-bf2f((unsigned short)gv.y)));
    r.y = xv.y + g1 * (o1 - xv.y);
  }
  {
    const float o2 = bf2f((unsigned short)ov.z);
    const float g2 = 1.f / (1.f + __expf(-bf2f((unsigned short)gv.z)));
    r.z = xv.z + g2 * (o2 - xv.z);
  }
  {
    const float o3 = bf2f((unsigned short)ov.w);
    const float g3 = 1.f / (1.f + __expf(-bf2f((unsigned short)gv.w)));
    r.w = xv.w + g3 * (o3 - xv.w);
  }
  *(float4*)(y + i) = r;
}

extern "C" void kernel_launch(void* const* d_in, const int* in_sizes, int n_in,
                              void* d_out, int out_size, void* d_ws, size_t ws_size,
                              hipStream_t stream) {
  (void)in_sizes; (void)n_in; (void)out_size; (void)ws_size;
  const float* x   = (const float*)d_in[0];
  const float* kg  = (const float*)d_in[1];
  const float* Wq  = (const float*)d_in[2];
  const float* bq  = (const float*)d_in[3];
  const float* Wk  = (const float*)d_in[4];
  const float* bk  = (const float*)d_in[5];
  const float* Wv  = (const float*)d_in[6];
  const float* bv  = (const float*)d_in[7];
  const float* Wkk = (const float*)d_in[8];
  const float* bkk = (const float*)d_in[9];
  const float* Wkv = (const float*)d_in[10];
  const float* bkv = (const float*)d_in[11];
  const float* Wo  = (const float*)d_in[12];
  const float* bo  = (const float*)d_in[13];
  const float* Wg  = (const float*)d_in[14];
  const float* bg  = (const float*)d_in[15];
  float* y = (float*)d_out;

  char* ws = (char*)d_ws;
  size_t off = 0;
  auto take = [&](size_t bytes) {
    char* p = ws + off;
    off += (bytes + 255) & ~(size_t)255;
    return p;
  };
  ushort_t* xh   = (ushort_t*)take((size_t)4096 * 1024 * 2);
  ushort_t* kgh  = (ushort_t*)take((size_t)512 * 1024 * 2);
  ushort_t* WB1  = (ushort_t*)take((size_t)3072 * 1024 * 2);
  ushort_t* WB2  = (ushort_t*)take((size_t)2048 * 1024 * 2);
  ushort_t* WB3  = (ushort_t*)take((size_t)2048 * 1024 * 2);
  ushort_t* Qg   = (ushort_t*)take((size_t)32 * 2048 * 64 * 2);
  ushort_t* Kaug = (ushort_t*)take((size_t)32 * 2304 * 64 * 2);
  ushort_t* Vt   = (ushort_t*)take((size_t)32 * 2304 * 64 * 2);
  ushort_t* Og   = (ushort_t*)take((size_t)4096 * 1024 * 2);
  ushort_t* OUTb = (ushort_t*)take((size_t)4096 * 1024 * 2);
  ushort_t* GLb  = (ushort_t*)take((size_t)4096 * 1024 * 2);
  float* kgm     = (float*)take(2048 * 4);
  float* g2      = (float*)take(2048 * 4);

  k_cvt_all<<<11776, 256, 0, stream>>>(x, kg, Wq, Wk, Wv, Wkk, Wkv, Wo, Wg,
                                       xh, kgh, WB1, WB2, WB3);
  k_kgmean<<<8, 256, 0, stream>>>(kg, kgm);
  k_g2<<<512, 256, 0, stream>>>(kgm, Wg, bg, g2);

  k_gemm<0><<<dim3(32, 24), 256, 0, stream>>>(xh, WB1, bq, bk, bv, nullptr, Qg, Kaug, Vt);
  k_gemm<1><<<dim3(4, 16), 256, 0, stream>>>(kgh, WB2, bkk, bkv, nullptr, nullptr, nullptr, Kaug, Vt);
  k_attn<<<dim3(32, 32), 256, 0, stream>>>(Qg, Kaug, Vt, Og);
  k_gemm<2><<<dim3(32, 16), 256, 0, stream>>>(Og, WB3, bo, nullptr, nullptr, g2, OUTb, GLb, nullptr);
  k_final<<<4096, 256, 0, stream>>>(x, OUTb, GLb, y);
}

// Round 5
// 190.618 us; speedup vs baseline: 1.5315x; 1.1339x over previous
//
#include <hip/hip_runtime.h>
#include <stdint.h>

typedef unsigned short ushort_t;
typedef __attribute__((ext_vector_type(8))) short short8;
typedef __attribute__((ext_vector_type(4))) short short4v;
typedef __attribute__((ext_vector_type(4))) float f32x4;
typedef __attribute__((ext_vector_type(4))) unsigned uintx4;

#define DEV static __device__ __forceinline__

DEV unsigned short f2bf(float f) {
  unsigned u = __builtin_bit_cast(unsigned, f);
  u += 0x7fffu + ((u >> 16) & 1u);
  return (unsigned short)(u >> 16);
}
DEV float bf2f(unsigned short b) {
  return __builtin_bit_cast(float, (unsigned)b << 16);
}

DEV void gl16(const void* g, void* l) {
  __builtin_amdgcn_global_load_lds(
      (__attribute__((address_space(1))) char*)(unsigned long long)g,
      (__attribute__((address_space(3))) char*)(unsigned)(unsigned long long)l,
      16, 0, 0);
}

DEV f32x4 mfma_bf16(short8 a, short8 b, f32x4 c) {
  return __builtin_amdgcn_mfma_f32_16x16x32_bf16(a, b, c, 0, 0, 0);
}

DEV unsigned cvtpk(float lo, float hi) {
  unsigned r;
  asm("v_cvt_pk_bf16_f32 %0, %1, %2" : "=v"(r) : "v"(lo), "v"(hi));
  return r;
}
DEV void swap_net(unsigned& a, unsigned& b) {
  asm("v_permlane32_swap_b32 %0, %1" : "+v"(a), "+v"(b));
  asm("v_permlane16_swap_b32 %0, %1" : "+v"(a), "+v"(b));
}
DEV float redmax4(float x) {
  unsigned a = __builtin_bit_cast(unsigned, x), b = a;
  asm("v_permlane16_swap_b32 %0, %1" : "+v"(a), "+v"(b));
  float y = fmaxf(__builtin_bit_cast(float, a), __builtin_bit_cast(float, b));
  unsigned c = __builtin_bit_cast(unsigned, y), d = c;
  asm("v_permlane32_swap_b32 %0, %1" : "+v"(c), "+v"(d));
  return fmaxf(__builtin_bit_cast(float, c), __builtin_bit_cast(float, d));
}
DEV float lanebcast(float v, int srclane) {
  return __builtin_bit_cast(float,
      __builtin_amdgcn_ds_bpermute(srclane * 4, __builtin_bit_cast(int, v)));
}

// ---------------- consolidated converts ----------------
__global__ __launch_bounds__(256) void k_cvt_all(
    const float* __restrict__ x, const float* __restrict__ kg,
    const float* __restrict__ Wq, const float* __restrict__ Wk, const float* __restrict__ Wv,
    const float* __restrict__ Wkk, const float* __restrict__ Wkv,
    const float* __restrict__ Wo, const float* __restrict__ Wg,
    ushort_t* __restrict__ xh, ushort_t* __restrict__ kgh,
    ushort_t* __restrict__ WB1, ushort_t* __restrict__ WB2, ushort_t* __restrict__ WB3) {
  const int b = blockIdx.x;
  if (b >= 10752) {
    const int i = (b - 10752) * 256 + threadIdx.x;
    const int r = i >> 8, c = (i & 255) * 4;
    const float4 v = *(const float4*)(Wg + (size_t)r * 2048 + c);
    short4v o;
    o.x = (short)f2bf(v.x); o.y = (short)f2bf(v.y); o.z = (short)f2bf(v.z); o.w = (short)f2bf(v.w);
    *(short4v*)(WB3 + 1048576 + (size_t)r * 1024 + c) = o;
    return;
  }
  const float* src;
  ushort_t* dst;
  int off;
  if (b < 4096)       { src = x;   dst = xh;            off = b; }
  else if (b < 4608)  { src = kg;  dst = kgh;           off = b - 4096; }
  else if (b < 5632)  { src = Wq;  dst = WB1;           off = b - 4608; }
  else if (b < 6656)  { src = Wk;  dst = WB1 + 1048576; off = b - 5632; }
  else if (b < 7680)  { src = Wv;  dst = WB1 + 2097152; off = b - 6656; }
  else if (b < 8704)  { src = Wkk; dst = WB2;           off = b - 7680; }
  else if (b < 9728)  { src = Wkv; dst = WB2 + 1048576; off = b - 8704; }
  else                { src = Wo;  dst = WB3;           off = b - 9728; }
  const int i = off * 1024 + threadIdx.x * 4;
  const float4 v = *(const float4*)(src + i);
  short4v o;
  o.x = (short)f2bf(v.x); o.y = (short)f2bf(v.y); o.z = (short)f2bf(v.z); o.w = (short)f2bf(v.w);
  *(short4v*)(dst + i) = o;
}

__global__ __launch_bounds__(256) void k_kgmean(const float* __restrict__ kg, float* __restrict__ out) {
  const int i = blockIdx.x * 256 + threadIdx.x;
  const int b = i >> 10, d = i & 1023;
  float s = 0.f;
  #pragma unroll 4
  for (int e = 0; e < 256; e++) s += kg[((size_t)b * 256 + e) * 1024 + d];
  out[i] = s * (1.0f / 256.0f);
}

__global__ __launch_bounds__(256) void k_g2(const float* __restrict__ kgm, const float* __restrict__ Wg,
                                            const float* __restrict__ bg, float* __restrict__ g2) {
  const int w = threadIdx.x >> 6, l = threadIdx.x & 63;
  const int idx = blockIdx.x * 4 + w;
  const int b = idx >> 10, n = idx & 1023;
  const float* wr = Wg + (size_t)n * 2048 + 1024;
  const float* mb = kgm + b * 1024;
  float s = 0.f;
  #pragma unroll
  for (int j = 0; j < 16; j++) s += mb[j * 64 + l] * wr[j * 64 + l];
  #pragma unroll
  for (int m = 32; m >= 1; m >>= 1) s += __shfl_xor(s, m);
  if (l == 0) g2[idx] = s + bg[n];
}

// ---------------- merged QKV + KG projection GEMM ----------------
// bx<32 : A=xh (M=4096), Bw=WB1 (N=3072): sec0->Qg(scaled), sec1->Kaug(l), sec2->Vt(l)
// bx>=32: A=kgh (M=512), Bw=WB2 (N=2048): sec0->Kaug(e), sec1->Vt(e)   (by<16 only)
__global__ __launch_bounds__(256) void k_gemm_qkv(
    const ushort_t* __restrict__ xh, const ushort_t* __restrict__ WB1,
    const ushort_t* __restrict__ kgh, const ushort_t* __restrict__ WB2,
    const float* __restrict__ bq, const float* __restrict__ bk, const float* __restrict__ bv,
    const float* __restrict__ bkk, const float* __restrict__ bkv,
    ushort_t* __restrict__ Qg, ushort_t* __restrict__ Kaug, ushort_t* __restrict__ Vt) {
  const bool iskg = blockIdx.x >= 32;
  if (iskg && blockIdx.y >= 16) return;
  __shared__ __align__(16) ushort_t SH[16384];  // As[2][4096] | Bs[2][4096]; reused for V transpose
  const int tid = threadIdx.x;
  const int w = tid >> 6, l = tid & 63;
  const int wr = w >> 1, wc = w & 1;
  const int fr = l & 15, fg = l >> 4;
  const int m0 = (iskg ? (blockIdx.x - 32) : blockIdx.x) * 128;
  const int n0 = blockIdx.y * 128;
  const int srow = tid >> 2, sseg = tid & 3;
  const ushort_t* A  = iskg ? kgh : xh;
  const ushort_t* Bw = iskg ? WB2 : WB1;
  const ushort_t* ga = A + (size_t)(m0 + srow) * 1024 + sseg * 8;
  const ushort_t* gb = Bw + (size_t)(n0 + srow) * 1024 + sseg * 8;
  f32x4 acc[4][4] = {};

  auto stage = [&](int nb, int kt) {
    char* lA = (char*)SH + nb * 8192 + w * 1024;
    char* lB = (char*)SH + 16384 + nb * 8192 + w * 1024;
    const ushort_t* gA = ga + kt * 32;
    const ushort_t* gB = gb + kt * 32;
    gl16(gA, lA);
    gl16(gA + 64 * 1024, lA + 4096);
    gl16(gB, lB);
    gl16(gB + 64 * 1024, lB + 4096);
  };

  stage(0, 0);
  __syncthreads();
  int cur = 0;
  for (int kt = 0; kt < 32; kt++) {
    if (kt < 31) stage(cur ^ 1, kt + 1);
    const short* Ab = (const short*)(SH + cur * 4096);
    const short* Bb = (const short*)(SH + 8192 + cur * 4096);
    short8 af[4], bfr[4];
    #pragma unroll
    for (int i = 0; i < 4; i++) {
      af[i]  = *(const short8*)(Ab + (wr * 64 + i * 16 + fr) * 32 + fg * 8);
      bfr[i] = *(const short8*)(Bb + (wc * 64 + i * 16 + fr) * 32 + fg * 8);
    }
    #pragma unroll
    for (int i = 0; i < 4; i++)
      #pragma unroll
      for (int j = 0; j < 4; j++)
        acc[i][j] = mfma_bf16(af[i], bfr[j], acc[i][j]);
    __syncthreads();
    cur ^= 1;
  }

  const int sec = n0 >> 10;
  const bool isV = iskg ? (sec == 1) : (sec == 2);

  if (isV) {
    // ---- V path: transpose via LDS, coalesced Vt writes ----
    const float* bV = iskg ? bkv : bv;
    #pragma unroll
    for (int i = 0; i < 4; i++) {
      #pragma unroll
      for (int j = 0; j < 4; j++) {
        const int ml0 = wr * 64 + i * 16 + fg * 4;
        const int nl = wc * 64 + j * 16 + fr;
        const float bb = bV[(n0 & 1023) + nl];
        short4v pk;
        #pragma unroll
        for (int r = 0; r < 4; r++) pk[r] = (short)f2bf(acc[i][j][r] + bb);
        *(short4v*)(SH + nl * 128 + (ml0 ^ ((nl & 7) << 3))) = pk;
      }
    }
    __syncthreads();
    const int row = tid >> 1, half = tid & 1;           // row = n_local 0..127
    const int h = ((n0 & 1023) >> 6) + (row >> 6);
    const int d = row & 63;
    const int b = iskg ? (m0 >> 8) : (m0 >> 11);
    const int colbase = iskg ? (2048 + (m0 & 255)) : (m0 & 2047);
    ushort_t* dst = Vt + ((size_t)(b * 16 + h) * 64 + d) * 2304 + colbase + half * 64;
    const ushort_t* srow2 = SH + row * 128;
    #pragma unroll
    for (int k2 = 0; k2 < 8; k2++) {
      const int me = (half * 64 + k2 * 8) ^ ((row & 7) << 3);
      *(short8*)(dst + k2 * 8) = *(const short8*)(srow2 + me);
    }
    return;
  }

  #pragma unroll
  for (int i = 0; i < 4; i++) {
    #pragma unroll
    for (int j = 0; j < 4; j++) {
      #pragma unroll
      for (int r = 0; r < 4; r++) {
        const int m = m0 + wr * 64 + i * 16 + fg * 4 + r;
        const int nn = (n0 & 1023) + wc * 64 + j * 16 + fr;
        const int h = nn >> 6, d = nn & 63;
        const float v = acc[i][j][r];
        if (iskg) {
          const int b = m >> 8, e = m & 255;
          Kaug[((size_t)(b * 16 + h) * 2304 + 2048 + e) * 64 + d] = f2bf(v + bkk[nn]);
        } else {
          const int b = m >> 11, lq = m & 2047;
          if (sec == 0)
            Qg[((size_t)(b * 16 + h) * 2048 + lq) * 64 + d] = f2bf((v + bq[nn]) * 0.18033688f); // 0.125*log2e
          else
            Kaug[((size_t)(b * 16 + h) * 2304 + lq) * 64 + d] = f2bf(v + bk[nn]);
        }
      }
    }
  }
}

// ---------------- output GEMM: OUT = Og*Wo^T + bo ; GL = Og*Wg1^T + g2 ----------------
__global__ __launch_bounds__(256) void k_gemm2(
    const ushort_t* __restrict__ A, const ushort_t* __restrict__ Bw,
    const float* __restrict__ bias0, const float* __restrict__ g2v,
    ushort_t* __restrict__ o0, ushort_t* __restrict__ o1) {
  __shared__ __align__(16) ushort_t As[2][128 * 32];
  __shared__ __align__(16) ushort_t Bs[2][128 * 32];
  const int tid = threadIdx.x;
  const int w = tid >> 6, l = tid & 63;
  const int wr = w >> 1, wc = w & 1;
  const int fr = l & 15, fg = l >> 4;
  const int m0 = blockIdx.x * 128, n0 = blockIdx.y * 128;
  const int srow = tid >> 2, sseg = tid & 3;
  const ushort_t* ga = A + (size_t)(m0 + srow) * 1024 + sseg * 8;
  const ushort_t* gb = Bw + (size_t)(n0 + srow) * 1024 + sseg * 8;
  f32x4 acc[4][4] = {};

  auto stage = [&](int nb, int kt) {
    char* lA = (char*)&As[nb][0] + w * 1024;
    char* lB = (char*)&Bs[nb][0] + w * 1024;
    const ushort_t* gA = ga + kt * 32;
    const ushort_t* gB = gb + kt * 32;
    gl16(gA, lA);
    gl16(gA + 64 * 1024, lA + 4096);
    gl16(gB, lB);
    gl16(gB + 64 * 1024, lB + 4096);
  };

  stage(0, 0);
  __syncthreads();
  int cur = 0;
  for (int kt = 0; kt < 32; kt++) {
    if (kt < 31) stage(cur ^ 1, kt + 1);
    const short* Ab = (const short*)&As[cur][0];
    const short* Bb = (const short*)&Bs[cur][0];
    short8 af[4], bfr[4];
    #pragma unroll
    for (int i = 0; i < 4; i++) {
      af[i]  = *(const short8*)(Ab + (wr * 64 + i * 16 + fr) * 32 + fg * 8);
      bfr[i] = *(const short8*)(Bb + (wc * 64 + i * 16 + fr) * 32 + fg * 8);
    }
    #pragma unroll
    for (int i = 0; i < 4; i++)
      #pragma unroll
      for (int j = 0; j < 4; j++)
        acc[i][j] = mfma_bf16(af[i], bfr[j], acc[i][j]);
    __syncthreads();
    cur ^= 1;
  }

  const int sec = n0 >> 10;
  #pragma unroll
  for (int i = 0; i < 4; i++) {
    #pragma unroll
    for (int j = 0; j < 4; j++) {
      #pragma unroll
      for (int r = 0; r < 4; r++) {
        const int m = m0 + wr * 64 + i * 16 + fg * 4 + r;
        const int nn = (n0 & 1023) + wc * 64 + j * 16 + fr;
        const float v = acc[i][j][r];
        if (sec == 0)
          o0[(size_t)m * 1024 + nn] = f2bf(v + bias0[nn]);
        else
          o1[(size_t)m * 1024 + nn] = f2bf(v + g2v[(m >> 11) * 1024 + nn]);
      }
    }
  }
}

// ---------------- flash attention (QBLK=64, XCD swizzle, gl16 staging) -------
// Qg [bh][2048][64] (pre-scaled by 0.125*log2e), Kg [bh][2304][64], Vtg [bh][64][2304],
// Og [b*2048][1024] (all bf16). exp in base-2 domain.
__global__ __launch_bounds__(256, 4) void k_attn(
    const ushort_t* __restrict__ Qg, const ushort_t* __restrict__ Kg,
    const ushort_t* __restrict__ Vtg, ushort_t* __restrict__ Og) {
  __shared__ __align__(16) ushort_t Ks[2][64 * 64];   // XOR-swizzled [kv][d]
  __shared__ __align__(16) ushort_t Vs[2][64 * 64];   // XOR-swizzled [d][kv]
  const int tid = threadIdx.x;
  const int w = tid >> 6, l = tid & 63;
  const int fr = l & 15, fg = l >> 4;

  // XCD-aware swizzle: concentrate each bh's q-blocks on one XCD
  const int id = blockIdx.y * gridDim.x + blockIdx.x;      // 0..1023
  const int bh = (id & 7) * 4 + ((id >> 3) >> 5);
  const int q0 = ((id >> 3) & 31) * 64 + w * 16;

  short8 qf[2];
  {
    const short* qrow = (const short*)(Qg + ((size_t)bh * 2048 + q0 + fr) * 64);
    qf[0] = *(const short8*)(qrow + fg * 8);
    qf[1] = *(const short8*)(qrow + 32 + fg * 8);
  }

  constexpr short ONE = 0x3F80;  // bf16 1.0
  const short8 ones = {ONE, ONE, ONE, ONE, ONE, ONE, ONE, ONE};

  f32x4 o[4] = {};
  f32x4 lacc = {};
  float mrun = -1.0e30f;

  // gl16 staging: linear LDS dst, pre-swizzled global source (XOR bit4 within rows)
  const int rsub = tid >> 3;                                   // 0..31
  const int cS = ((tid & 7) * 16) ^ ((rsub & 7) << 4);         // swizzled col byte (const)
  const char* kbase = (const char*)(Kg + (size_t)bh * 2304 * 64);
  const char* vbase = (const char*)(Vtg + (size_t)bh * 64 * 2304);

  auto stage = [&](int nb, int tile) {
    #pragma unroll
    for (int j = 0; j < 2; j++) {
      const int row = j * 32 + rsub;
      gl16(kbase + (size_t)(tile * 64 + row) * 128 + cS,
           (char*)&Ks[nb][0] + j * 4096 + tid * 16);
      gl16(vbase + (size_t)row * 4608 + tile * 128 + cS,
           (char*)&Vs[nb][0] + j * 4096 + tid * 16);
    }
  };

  stage(0, 0);

  const int rswz = (fr & 7) << 4;

  for (int mt = 0; mt < 36; mt++) {
    __syncthreads();
    if (mt < 35) stage((mt + 1) & 1, mt + 1);

    const char* Kb = (const char*)&Ks[mt & 1][0];
    const char* Vb = (const char*)&Vs[mt & 1][0];

    // swapped QK^T: lane holds S^T: q=fr, kv = t*16 + fg*4 + r
    f32x4 s[4];
    #pragma unroll
    for (int t = 0; t < 4; t++) {
      const int rb = (t * 16 + fr) * 128 + fg * 16;
      const short8 k0 = *(const short8*)(Kb + (rb ^ rswz));
      const short8 k1 = *(const short8*)(Kb + ((rb + 64) ^ rswz));
      f32x4 z = {};
      z = mfma_bf16(k0, qf[0], z);
      z = mfma_bf16(k1, qf[1], z);
      s[t] = z;
    }

    // online softmax (base-2), per-lane scalar running max (q = fr)
    float m = s[0][0];
    #pragma unroll
    for (int t = 0; t < 4; t++)
      #pragma unroll
      for (int r = 0; r < 4; r++) m = fmaxf(m, s[t][r]);
    const float mx = redmax4(m);
    if (__any(mx - mrun > 11.5416f)) {
      const float mn = fmaxf(mrun, mx);
      const float al = __builtin_amdgcn_exp2f(mrun - mn);
      mrun = mn;
      float ab[4];
      #pragma unroll
      for (int r = 0; r < 4; r++) ab[r] = lanebcast(al, fg * 4 + r);
      #pragma unroll
      for (int r = 0; r < 4; r++) {
        lacc[r] *= ab[r];
        #pragma unroll
        for (int dt = 0; dt < 4; dt++) o[dt][r] *= ab[r];
      }
    }
    #pragma unroll
    for (int t = 0; t < 4; t++)
      #pragma unroll
      for (int r = 0; r < 4; r++)
        s[t][r] = __builtin_amdgcn_exp2f(s[t][r] - mrun);

    // PV: assemble P A-frags in-register; l-sum via ones-MFMA
    #pragma unroll
    for (int c = 0; c < 2; c++) {
      unsigned a0 = cvtpk(s[2 * c][0], s[2 * c][1]);
      unsigned b0 = cvtpk(s[2 * c + 1][0], s[2 * c + 1][1]);
      unsigned a1 = cvtpk(s[2 * c][2], s[2 * c][3]);
      unsigned b1 = cvtpk(s[2 * c + 1][2], s[2 * c + 1][3]);
      swap_net(a0, b0);
      swap_net(a1, b1);
      uintx4 u;
      u.x = a0; u.y = a1; u.z = b0; u.w = b1;
      const short8 pf = __builtin_bit_cast(short8, u);
      lacc = mfma_bf16(pf, ones, lacc);
      #pragma unroll
      for (int dt = 0; dt < 4; dt++) {
        const int vb2 = ((dt * 16 + fr) * 128) + fg * 16 + c * 64;
        const short8 vf = *(const short8*)(Vb + (vb2 ^ rswz));
        o[dt] = mfma_bf16(pf, vf, o[dt]);
      }
    }
  }

  const int b = bh >> 4, h = bh & 15;
  #pragma unroll
  for (int r = 0; r < 4; r++) {
    const float inv = 1.0f / lacc[r];
    const int q = q0 + fg * 4 + r;
    ushort_t* orow = Og + ((size_t)b * 2048 + q) * 1024 + h * 64;
    #pragma unroll
    for (int dt = 0; dt < 4; dt++) orow[dt * 16 + fr] = f2bf(o[dt][r] * inv);
  }
}

// ---------------- final mix ----------------
__global__ __launch_bounds__(256) void k_final(const float* __restrict__ x,
                                               const ushort_t* __restrict__ OUT,
                                               const ushort_t* __restrict__ GL,
                                               float* __restrict__ y) {
  const int i = (blockIdx.x * 256 + threadIdx.x) * 4;
  const float4 xv = *(const float4*)(x + i);
  const short4v ov = *(const short4v*)((const short*)OUT + i);
  const short4v gv = *(const short4v*)((const short*)GL + i);
  float4 r;
  {
    const float o0 = bf2f((unsigned short)ov.x);
    const float g0 = 1.f / (1.f + __expf(-bf2f((unsigned short)gv.x)));
    r.x = xv.x + g0 * (o0 - xv.x);
  }
  {
    const float o1 = bf2f((unsigned short)ov.y);
    const float g1 = 1.f / (1.f + __expf(-bf2f((unsigned short)gv.y)));
    r.y = xv.y + g1 * (o1 - xv.y);
  }
  {
    const float o2 = bf2f((unsigned short)ov.z);
    const float g2 = 1.f / (1.f + __expf(-bf2f((unsigned short)gv.z)));
    r.z = xv.z + g2 * (o2 - xv.z);
  }
  {
    const float o3 = bf2f((unsigned short)ov.w);
    const float g3 = 1.f / (1.f + __expf(-bf2f((unsigned short)gv.w)));
    r.w = xv.w + g3 * (o3 - xv.w);
  }
  *(float4*)(y + i) = r;
}

extern "C" void kernel_launch(void* const* d_in, const int* in_sizes, int n_in,
                              void* d_out, int out_size, void* d_ws, size_t ws_size,
                              hipStream_t stream) {
  (void)in_sizes; (void)n_in; (void)out_size; (void)ws_size;
  const float* x   = (const float*)d_in[0];
  const float* kg  = (const float*)d_in[1];
  const float* Wq  = (const float*)d_in[2];
  const float* bq  = (const float*)d_in[3];
  const float* Wk  = (const float*)d_in[4];
  const float* bk  = (const float*)d_in[5];
  const float* Wv  = (const float*)d_in[6];
  const float* bv  = (const float*)d_in[7];
  const float* Wkk = (const float*)d_in[8];
  const float* bkk = (const float*)d_in[9];
  const float* Wkv = (const float*)d_in[10];
  const float* bkv = (const float*)d_in[11];
  const float* Wo  = (const float*)d_in[12];
  const float* bo  = (const float*)d_in[13];
  const float* Wg  = (const float*)d_in[14];
  const float* bg  = (const float*)d_in[15];
  float* y = (float*)d_out;

  char* ws = (char*)d_ws;
  size_t off = 0;
  auto take = [&](size_t bytes) {
    char* p = ws + off;
    off += (bytes + 255) & ~(size_t)255;
    return p;
  };
  ushort_t* xh   = (ushort_t*)take((size_t)4096 * 1024 * 2);
  ushort_t* kgh  = (ushort_t*)take((size_t)512 * 1024 * 2);
  ushort_t* WB1  = (ushort_t*)take((size_t)3072 * 1024 * 2);
  ushort_t* WB2  = (ushort_t*)take((size_t)2048 * 1024 * 2);
  ushort_t* WB3  = (ushort_t*)take((size_t)2048 * 1024 * 2);
  ushort_t* Qg   = (ushort_t*)take((size_t)32 * 2048 * 64 * 2);
  ushort_t* Kaug = (ushort_t*)take((size_t)32 * 2304 * 64 * 2);
  ushort_t* Vt   = (ushort_t*)take((size_t)32 * 2304 * 64 * 2);
  ushort_t* Og   = (ushort_t*)take((size_t)4096 * 1024 * 2);
  ushort_t* OUTb = (ushort_t*)take((size_t)4096 * 1024 * 2);
  ushort_t* GLb  = (ushort_t*)take((size_t)4096 * 1024 * 2);
  float* kgm     = (float*)take(2048 * 4);
  float* g2      = (float*)take(2048 * 4);

  k_cvt_all<<<11776, 256, 0, stream>>>(x, kg, Wq, Wk, Wv, Wkk, Wkv, Wo, Wg,
                                       xh, kgh, WB1, WB2, WB3);
  k_kgmean<<<8, 256, 0, stream>>>(kg, kgm);
  k_g2<<<512, 256, 0, stream>>>(kgm, Wg, bg, g2);

  k_gemm_qkv<<<dim3(36, 24), 256, 0, stream>>>(xh, WB1, kgh, WB2,
                                               bq, bk, bv, bkk, bkv, Qg, Kaug, Vt);
  k_attn<<<dim3(32, 32), 256, 0, stream>>>(Qg, Kaug, Vt, Og);
  k_gemm2<<<dim3(32, 16), 256, 0, stream>>>(Og, WB3, bo, g2, OUTb, GLb);
  k_final<<<4096, 256, 0, stream>>>(x, OUTb, GLb, y);
}